// Round 15
// baseline (83.444 us; speedup 1.0000x reference)
//
#include <hip/hip_runtime.h>
#include <hip/hip_bf16.h>

#define NN 2048
#define KD 512
#define ODIM 512
#define NHEAD 8
#define HD 64
#define NEG 0.2f

typedef float f32x4 __attribute__((ext_vector_type(4)));
typedef short bf16x8 __attribute__((ext_vector_type(8)));
typedef short bf16x4 __attribute__((ext_vector_type(4)));
typedef unsigned int u32x4 __attribute__((ext_vector_type(4)));
typedef unsigned long long u64;
typedef unsigned int u32;

__device__ __forceinline__ short tob(float f) {
  __hip_bfloat16 h = __float2bfloat16(f);
  return *reinterpret_cast<short*>(&h);
}

// async global -> LDS; LDS dest = uniform base + lane*16
__device__ __forceinline__ void gl_lds16(const void* g, void* l) {
  __builtin_amdgcn_global_load_lds(
      (const __attribute__((address_space(1))) u32*)g,
      (__attribute__((address_space(3))) u32*)l, 16, 0, 0);
}

__device__ __forceinline__ u32 to_lds(const void* p) {
  return (u32)(size_t)(const __attribute__((address_space(3))) char*)p;
}

// inline-asm ds_read_b128: opaque to the waitcnt legalizer (no auto drains)
#define DSR(dst, addr, OFFLIT)                      \
  asm volatile("ds_read_b128 %0, %1 offset:" OFFLIT \
               : "=v"(dst)                          \
               : "v"(addr))

// ---------------------------------------------------------------------------
// prep: blocks 0..1023   pack adj -> bitmask
//       blocks 1024..1151 Xf: X (f32) -> bf16 in MFMA-A-fragment order
//       blocks 1152..1215 Bf: W (f32) -> bf16 in MFMA-B-fragment order
// ---------------------------------------------------------------------------
__global__ __launch_bounds__(256) void prep(const float* __restrict__ X,
                                            const float* __restrict__ W,
                                            const int* __restrict__ adj,
                                            short* __restrict__ Xf,
                                            short* __restrict__ Bf,
                                            unsigned short* __restrict__ bits) {
  __shared__ float sbuf[16 * 516];
  const int b = blockIdx.x;
  const int t = threadIdx.x;

  if (b < 1024) {  // ---- adj pack ----
    const int T = b * 256 + t;
    const int row = T >> 7, g = T & 127;
    const int* p = adj + (size_t)row * NN + g * 16;
    u32 m = 0;
#pragma unroll
    for (int q = 0; q < 4; ++q) {
      const int4 v = *(const int4*)&p[q * 4];
      m |= (v.x > 0 ? 1u : 0u) << (q * 4);
      m |= (v.y > 0 ? 2u : 0u) << (q * 4);
      m |= (v.z > 0 ? 4u : 0u) << (q * 4);
      m |= (v.w > 0 ? 8u : 0u) << (q * 4);
    }
    bits[T] = (unsigned short)m;
    return;
  }

  if (b < 1024 + 128) {  // ---- X -> Xf ----
    const int xb = b - 1024;
#pragma unroll
    for (int q = 0; q < 8; ++q) {
      const int flat = q * 256 + t;
      const int row = flat >> 7, c4 = flat & 127;
      const float4 v = *(const float4*)&X[(size_t)(xb * 16 + row) * KD + c4 * 4];
      *(float4*)&sbuf[row * 516 + c4 * 4] = v;
    }
    __syncthreads();
#pragma unroll
    for (int c = 0; c < 4; ++c) {
      const int s = c * 256 + t;
      const int l = s & 63;
      const int col = l & 15, kg = (l >> 4) & 3;
      const int k0 = (s >> 6) * 32 + kg * 8;
      bf16x8 o;
#pragma unroll
      for (int u = 0; u < 8; ++u) o[u] = tob(sbuf[col * 516 + k0 + u]);
      *(bf16x8*)&Xf[((size_t)xb * 1024 + s) * 8] = o;
    }
    return;
  }

  // ---- W -> Bf ----
  const int b2 = b - 1152;
  const int kb = b2 & 7, h = b2 >> 3;
  const int k0 = kb * 64;
#pragma unroll
  for (int q = 0; q < 4; ++q) {
    const int flat = q * 256 + t;
    const int kk = flat >> 4, o4 = (flat & 15) * 4;
    const float4 v = *(const float4*)&W[(size_t)(k0 + kk) * ODIM + h * 64 + o4];
    *(float4*)&sbuf[kk * 68 + o4] = v;
  }
  __syncthreads();
#pragma unroll
  for (int c = 0; c < 2; ++c) {
    const int s = c * 256 + t;
    const int ksl = s >> 8, nt = (s >> 6) & 3, l = s & 63;
    const int col = l & 15, kg = (l >> 4) & 3;
    const int kloc = ksl * 32 + kg * 8;
    const int od = nt * 16 + col;
    bf16x8 o;
#pragma unroll
    for (int u = 0; u < 8; ++u) o[u] = tob(sbuf[(kloc + u) * 68 + od]);
    const size_t off = (((size_t)(h * 4 + nt) * 16 + kb * 2 + ksl) * 64 + l) * 8;
    *(bf16x8*)&Bf[off] = o;
  }
}

// ---------------------------------------------------------------------------
// gemm_fused: grid (64, 8), 256 thr = 4 waves; block = 32 m-rows x head h.
// Waves split k; combine partials in LDS; waves 0-1 run the epilogue.
// ---------------------------------------------------------------------------
__global__ __launch_bounds__(256) void gemm_fused(
    const short* __restrict__ Xf, const short* __restrict__ Bf,
    const float* __restrict__ a, short* __restrict__ WhF,
    float2* __restrict__ esrcp, u32* __restrict__ edstp) {
  __shared__ float pbuf[4 * 4 * 64 * 4];  // 16 KB
  const int t = threadIdx.x;
  const int lane = t & 63, w = t >> 6;
  const int col = lane & 15, kgrp = lane >> 4;
  const int bx = blockIdx.x;
  const int h = blockIdx.y;
  const int i0 = bx * 32;

  {
    const int mtg = bx * 2 + (w & 1);  // global 16-row m-tile
    const int kh = w >> 1;             // k-half
    const short* ax = Xf + (size_t)mtg * 8192;
    const short* bxp = Bf + (size_t)h * 32768;

    f32x4 acc1[4] = {};
#pragma unroll
    for (int k2 = 0; k2 < 8; ++k2) {
      const int ks = kh * 8 + k2;
      const bf16x8 af = *(const bf16x8*)&ax[(ks * 64 + lane) * 8];
#pragma unroll
      for (int nt = 0; nt < 4; ++nt) {
        const bf16x8 bf = *(const bf16x8*)&bxp[((nt * 16 + ks) * 64 + lane) * 8];
        acc1[nt] = __builtin_amdgcn_mfma_f32_16x16x32_bf16(af, bf, acc1[nt], 0, 0, 0);
      }
    }
#pragma unroll
    for (int nt = 0; nt < 4; ++nt)
      *(f32x4*)&pbuf[((w * 4 + nt) * 64 + lane) * 4] = acc1[nt];
  }
  __syncthreads();

  if (w < 2) {
    f32x4 acc[4];
#pragma unroll
    for (int nt = 0; nt < 4; ++nt) {
      const f32x4 p0 = *(const f32x4*)&pbuf[((w * 4 + nt) * 64 + lane) * 4];
      const f32x4 p1 = *(const f32x4*)&pbuf[(((w + 2) * 4 + nt) * 64 + lane) * 4];
      acc[nt] = p0 + p1;
    }
    float asv[4], adv[4];
#pragma unroll
    for (int nt = 0; nt < 4; ++nt) {
      asv[nt] = a[nt * 16 + col];
      adv[nt] = a[64 + nt * 16 + col];
    }
    float ps[4], pd[4];
#pragma unroll
    for (int r = 0; r < 4; ++r) {
      float s1 = 0.f, s2 = 0.f;
#pragma unroll
      for (int nt = 0; nt < 4; ++nt) {
        s1 += acc[nt][r] * asv[nt];
        s2 += acc[nt][r] * adv[nt];
      }
      ps[r] = s1;
      pd[r] = s2;
    }
#pragma unroll
    for (int off = 1; off <= 8; off <<= 1) {
#pragma unroll
      for (int r = 0; r < 4; ++r) {
        ps[r] += __shfl_xor(ps[r], off);
        pd[r] += __shfl_xor(pd[r], off);
      }
    }
    // fragment-ordered WhF store: j-tile = bx>>1, within-tile half = bx&1
    {
      const size_t tbase = ((size_t)h * 32 + (bx >> 1)) * 4096;
      const int lp = (w * 2 + (kgrp >> 1)) * 16 + col;
      const int u0 = (kgrp & 1) * 4;
      const int slot_ks = bx & 1;
#pragma unroll
      for (int nt = 0; nt < 4; ++nt) {
        bf16x4 o;
#pragma unroll
        for (int r = 0; r < 4; ++r) o[r] = tob(acc[nt][r]);
        *(bf16x4*)&WhF[tbase + (size_t)(nt * 2 + slot_ks) * 512 + lp * 8 + u0] = o;
      }
    }
    if (col == 0) {
      const int mbase = i0 + w * 16 + kgrp * 4;
#pragma unroll
      for (int r = 0; r < 4; ++r) {
        const int n = mbase + r;
        esrcp[h * NN + n] = make_float2(__expf(ps[r]), __expf(NEG * ps[r]));
        const u32 lo = (u32)(unsigned short)tob(__expf(pd[r]));
        const u32 hi = (u32)(unsigned short)tob(__expf(NEG * pd[r]));
        edstp[h * NN + n] = (hi << 16) | lo;
      }
    }
  }
}

// ---------------------------------------------------------------------------
// attn_mfma: identical to round 13 (8 waves, jq-pair shared dbuf, vmcnt(4) +
// raw s_barrier, asm ds_read_b128, adj in registers).
// ---------------------------------------------------------------------------
__global__ __launch_bounds__(512, 4) void attn_mfma(
    const short* __restrict__ WhF, const unsigned char* __restrict__ adjbits,
    const float2* __restrict__ esrcp, const u32* __restrict__ edstp,
    float* __restrict__ out) {
  extern __shared__ __align__(16) char smem[];  // 4 jq x 18432 B = 73728 B
  const int t = threadIdx.x;
  const int lane = t & 63;
  const int wid = t >> 6;
  const int jq = wid & 3;
  const int mh = wid >> 2;
  const int col = lane & 15, kgrp = lane >> 4;
  const int h = blockIdx.y;
  const int i0 = blockIdx.x * 32;
  const int irow = i0 + mh * 16;

  char* qbase = smem + jq * 18432;
  char* dbuf = qbase;          // [2][8192] B-fragments (shared by the pair)
  char* elds = qbase + 16384;  // 2048 B edstp

  const short* tb = WhF + ((size_t)h * 32 + jq * 8) * 4096;
  const int jb = jq * 512;

  const float2 e0 = esrcp[h * NN + irow + col];
  const float A0 = e0.x, C0 = e0.y;

  u64 aw[8];
  {
    const unsigned char* rb = adjbits + (size_t)(irow + col) * (NN / 8) + jq * 64;
#pragma unroll
    for (int q = 0; q < 4; ++q) {
      const uint4 v = *(const uint4*)(rb + q * 16);
      aw[q * 2] = (u64)v.x | ((u64)v.y << 32);
      aw[q * 2 + 1] = (u64)v.z | ((u64)v.w << 32);
    }
  }

  bf16x8 ones;
#pragma unroll
  for (int u = 0; u < 8; ++u) ones[u] = (short)0x3F80;

  f32x4 acc[4] = {};
  f32x4 accd = {};

  const u32 lread = to_lds(dbuf) + (u32)lane * 16u;
  const u32 eread = to_lds(elds) + (u32)kgrp * 32u;

  // ---- prologue: this wave stages its half of edstp + tile-0 slots ----
  {
    gl_lds16(edstp + h * NN + jb + mh * 256 + lane * 4, elds + mh * 1024);
#pragma unroll
    for (int s = 0; s < 4; ++s) {
      const int slot = mh * 4 + s;
      gl_lds16(tb + slot * 512 + lane * 8, dbuf + slot * 1024);
    }
  }

#pragma unroll
  for (int tt = 0; tt < 8; ++tt) {
    const int cur = tt & 1, nxt = cur ^ 1;

    if (tt < 7) {
      const short* g = tb + (size_t)(tt + 1) * 4096;
      char* sb = dbuf + nxt * 8192;
#pragma unroll
      for (int s = 0; s < 4; ++s) {
        const int slot = mh * 4 + s;
        gl_lds16(g + slot * 512 + lane * 8, sb + slot * 1024);
      }
      asm volatile("s_waitcnt vmcnt(4)" ::: "memory");
    } else {
      asm volatile("s_waitcnt vmcnt(0)" ::: "memory");
    }
    __builtin_amdgcn_sched_barrier(0);
    __builtin_amdgcn_s_barrier();  // pair-join: partner's slots also landed

    const u32 abuf = lread + (u32)(cur * 8192);
    bf16x8 b0, b1, b2, b3, b4, b5, b6, b7;
    DSR(b0, abuf, "0");
    DSR(b1, abuf, "1024");
    DSR(b2, abuf, "2048");
    DSR(b3, abuf, "3072");
    DSR(b4, abuf, "4096");
    DSR(b5, abuf, "5120");
    DSR(b6, abuf, "6144");
    DSR(b7, abuf, "7168");
    u32x4 eq[4];
    switch (tt) {  // compile-time offsets (tt unrolled)
      case 0: DSR(eq[0], eread, "0");    DSR(eq[1], eread, "16");   DSR(eq[2], eread, "128");  DSR(eq[3], eread, "144");  break;
      case 1: DSR(eq[0], eread, "256");  DSR(eq[1], eread, "272");  DSR(eq[2], eread, "384");  DSR(eq[3], eread, "400");  break;
      case 2: DSR(eq[0], eread, "512");  DSR(eq[1], eread, "528");  DSR(eq[2], eread, "640");  DSR(eq[3], eread, "656");  break;
      case 3: DSR(eq[0], eread, "768");  DSR(eq[1], eread, "784");  DSR(eq[2], eread, "896");  DSR(eq[3], eread, "912");  break;
      case 4: DSR(eq[0], eread, "1024"); DSR(eq[1], eread, "1040"); DSR(eq[2], eread, "1152"); DSR(eq[3], eread, "1168"); break;
      case 5: DSR(eq[0], eread, "1280"); DSR(eq[1], eread, "1296"); DSR(eq[2], eread, "1408"); DSR(eq[3], eread, "1424"); break;
      case 6: DSR(eq[0], eread, "1536"); DSR(eq[1], eread, "1552"); DSR(eq[2], eread, "1664"); DSR(eq[3], eread, "1680"); break;
      default:DSR(eq[0], eread, "1792"); DSR(eq[1], eread, "1808"); DSR(eq[2], eread, "1920"); DSR(eq[3], eread, "1936"); break;
    }
    asm volatile("s_waitcnt lgkmcnt(0)" ::: "memory");
    __builtin_amdgcn_sched_barrier(0);

    bf16x8 af[2];
#pragma unroll
    for (int ks = 0; ks < 2; ++ks) {
      const u32 mb = (u32)(aw[tt] >> ((ks * 4 + kgrp) * 8)) & 0xffu;
      const u32x4 q0 = eq[ks * 2], q1 = eq[ks * 2 + 1];
      const u32 uw[8] = {q0[0], q0[1], q0[2], q0[3], q1[0], q1[1], q1[2], q1[3]};
#pragma unroll
      for (int u2 = 0; u2 < 8; ++u2) {
        const float B = __uint_as_float(uw[u2] << 16);
        const float D = __uint_as_float(uw[u2] & 0xffff0000u);
        float p = fmaxf(A0 * B, C0 * D);
        p = ((mb >> u2) & 1u) ? p : 0.f;
        af[ks][u2] = tob(p);
      }
    }

    __builtin_amdgcn_s_setprio(1);
    accd = __builtin_amdgcn_mfma_f32_16x16x32_bf16(af[0], ones, accd, 0, 0, 0);
    accd = __builtin_amdgcn_mfma_f32_16x16x32_bf16(af[1], ones, accd, 0, 0, 0);
    acc[0] = __builtin_amdgcn_mfma_f32_16x16x32_bf16(af[0], b0, acc[0], 0, 0, 0);
    acc[0] = __builtin_amdgcn_mfma_f32_16x16x32_bf16(af[1], b1, acc[0], 0, 0, 0);
    acc[1] = __builtin_amdgcn_mfma_f32_16x16x32_bf16(af[0], b2, acc[1], 0, 0, 0);
    acc[1] = __builtin_amdgcn_mfma_f32_16x16x32_bf16(af[1], b3, acc[1], 0, 0, 0);
    acc[2] = __builtin_amdgcn_mfma_f32_16x16x32_bf16(af[0], b4, acc[2], 0, 0, 0);
    acc[2] = __builtin_amdgcn_mfma_f32_16x16x32_bf16(af[1], b5, acc[2], 0, 0, 0);
    acc[3] = __builtin_amdgcn_mfma_f32_16x16x32_bf16(af[0], b6, acc[3], 0, 0, 0);
    acc[3] = __builtin_amdgcn_mfma_f32_16x16x32_bf16(af[1], b7, acc[3], 0, 0, 0);
    __builtin_amdgcn_s_setprio(0);

    __builtin_amdgcn_s_barrier();  // pair done reading cur -> safe to refill
  }

  // ---- cross-jq reduce (aliases dead staging LDS) ----
  __syncthreads();
  float* red = (float*)smem;  // [2 mh][4 jq][16 row][66]; den at col 64
  float* rw = red + (size_t)((mh * 4 + jq) * 16) * 66;
#pragma unroll
  for (int nt = 0; nt < 4; ++nt)
#pragma unroll
    for (int r = 0; r < 4; ++r)
      rw[(kgrp * 4 + r) * 66 + nt * 16 + col] = acc[nt][r];
  if (col == 0) {
#pragma unroll
    for (int r = 0; r < 4; ++r) rw[(kgrp * 4 + r) * 66 + 64] = accd[r];
  }
  __syncthreads();

  const int d = t & 63, idx = t >> 6;
#pragma unroll
  for (int rr = 0; rr < 4; ++rr) {
    const int row = rr * 8 + idx;
    const int mh2 = row >> 4, r16 = row & 15;
    float v = 0.f, dd = 0.f;
#pragma unroll
    for (int q = 0; q < 4; ++q) {
      const float* rb = red + (size_t)((mh2 * 4 + q) * 16 + r16) * 66;
      v += rb[d];
      dd += rb[64];
    }
    out[(size_t)(i0 + row) * ODIM + h * HD + d] = v / dd;
  }
}

// ---------------------------------------------------------------------------
// MEASUREMENT ROUND #2: chain + 3 extra attn launches (attn is idempotent).
// attn_warm + gap = (T - 34.9) / 3. Combined with R14 (warm chain = 29.6 us)
// this splits the time across {prep, gemm, attn}; round 16 acts on the
// dominant term.
// ---------------------------------------------------------------------------
extern "C" void kernel_launch(void* const* d_in, const int* in_sizes, int n_in,
                              void* d_out, int out_size, void* d_ws,
                              size_t ws_size, hipStream_t stream) {
  const float* x = (const float*)d_in[0];
  const int* adj = (const int*)d_in[1];
  const float* W = (const float*)d_in[2];
  const float* a = (const float*)d_in[3];
  float* out = (float*)d_out;

  char* ws = (char*)d_ws;
  short* WhF = (short*)ws;                                    // 2 MB
  short* Xf = (short*)(ws + (2 << 20));                       // 2 MB
  short* Bf = (short*)(ws + (4 << 20));                       // 512 KB
  unsigned short* bits =
      (unsigned short*)(ws + (4 << 20) + (512 << 10));        // 512 KB
  float2* esrcp = (float2*)(ws + (5 << 20));                  // 128 KB
  u32* edstp = (u32*)(ws + (5 << 20) + (128 << 10));          // 64 KB

  prep<<<1216, 256, 0, stream>>>(x, W, adj, Xf, Bf, bits);
  gemm_fused<<<dim3(64, 8), 256, 0, stream>>>(Xf, Bf, a, WhF, esrcp, edstp);
  attn_mfma<<<dim3(64, 8), 512, 73728, stream>>>(
      WhF, (const unsigned char*)bits, esrcp, edstp, out);
  attn_mfma<<<dim3(64, 8), 512, 73728, stream>>>(
      WhF, (const unsigned char*)bits, esrcp, edstp, out);
  attn_mfma<<<dim3(64, 8), 512, 73728, stream>>>(
      WhF, (const unsigned char*)bits, esrcp, edstp, out);
  attn_mfma<<<dim3(64, 8), 512, 73728, stream>>>(
      WhF, (const unsigned char*)bits, esrcp, edstp, out);
}

// Round 16
// 59.040 us; speedup vs baseline: 1.4133x; 1.4133x over previous
//
#include <hip/hip_runtime.h>
#include <hip/hip_bf16.h>

#define NN 2048
#define KD 512
#define ODIM 512
#define NHEAD 8
#define HD 64
#define NEG 0.2f

typedef float f32x4 __attribute__((ext_vector_type(4)));
typedef short bf16x8 __attribute__((ext_vector_type(8)));
typedef short bf16x4 __attribute__((ext_vector_type(4)));
typedef unsigned int u32x4 __attribute__((ext_vector_type(4)));
typedef unsigned long long u64;
typedef unsigned int u32;

__device__ __forceinline__ short tob(float f) {
  __hip_bfloat16 h = __float2bfloat16(f);
  return *reinterpret_cast<short*>(&h);
}

// async global -> LDS; LDS dest = uniform base + lane*16
__device__ __forceinline__ void gl_lds16(const void* g, void* l) {
  __builtin_amdgcn_global_load_lds(
      (const __attribute__((address_space(1))) u32*)g,
      (__attribute__((address_space(3))) u32*)l, 16, 0, 0);
}

__device__ __forceinline__ u32 to_lds(const void* p) {
  return (u32)(size_t)(const __attribute__((address_space(3))) char*)p;
}

// inline-asm ds_read_b128: opaque to the waitcnt legalizer (no auto drains)
#define DSR(dst, addr, OFFLIT)                      \
  asm volatile("ds_read_b128 %0, %1 offset:" OFFLIT \
               : "=v"(dst)                          \
               : "v"(addr))

// ---------------------------------------------------------------------------
// prep: blocks 0..1023   pack adj -> bitmask
//       blocks 1024..1151 Xf: X (f32) -> bf16 in MFMA-A-fragment order
//       blocks 1152..1215 Bf: W (f32) -> bf16 in MFMA-B-fragment order
// ---------------------------------------------------------------------------
__global__ __launch_bounds__(256) void prep(const float* __restrict__ X,
                                            const float* __restrict__ W,
                                            const int* __restrict__ adj,
                                            short* __restrict__ Xf,
                                            short* __restrict__ Bf,
                                            unsigned short* __restrict__ bits) {
  __shared__ float sbuf[16 * 516];
  const int b = blockIdx.x;
  const int t = threadIdx.x;

  if (b < 1024) {  // ---- adj pack ----
    const int T = b * 256 + t;
    const int row = T >> 7, g = T & 127;
    const int* p = adj + (size_t)row * NN + g * 16;
    u32 m = 0;
#pragma unroll
    for (int q = 0; q < 4; ++q) {
      const int4 v = *(const int4*)&p[q * 4];
      m |= (v.x > 0 ? 1u : 0u) << (q * 4);
      m |= (v.y > 0 ? 2u : 0u) << (q * 4);
      m |= (v.z > 0 ? 4u : 0u) << (q * 4);
      m |= (v.w > 0 ? 8u : 0u) << (q * 4);
    }
    bits[T] = (unsigned short)m;
    return;
  }

  if (b < 1024 + 128) {  // ---- X -> Xf ----
    const int xb = b - 1024;
#pragma unroll
    for (int q = 0; q < 8; ++q) {
      const int flat = q * 256 + t;
      const int row = flat >> 7, c4 = flat & 127;
      const float4 v = *(const float4*)&X[(size_t)(xb * 16 + row) * KD + c4 * 4];
      *(float4*)&sbuf[row * 516 + c4 * 4] = v;
    }
    __syncthreads();
#pragma unroll
    for (int c = 0; c < 4; ++c) {
      const int s = c * 256 + t;
      const int l = s & 63;
      const int col = l & 15, kg = (l >> 4) & 3;
      const int k0 = (s >> 6) * 32 + kg * 8;
      bf16x8 o;
#pragma unroll
      for (int u = 0; u < 8; ++u) o[u] = tob(sbuf[col * 516 + k0 + u]);
      *(bf16x8*)&Xf[((size_t)xb * 1024 + s) * 8] = o;
    }
    return;
  }

  // ---- W -> Bf ----
  const int b2 = b - 1152;
  const int kb = b2 & 7, h = b2 >> 3;
  const int k0 = kb * 64;
#pragma unroll
  for (int q = 0; q < 4; ++q) {
    const int flat = q * 256 + t;
    const int kk = flat >> 4, o4 = (flat & 15) * 4;
    const float4 v = *(const float4*)&W[(size_t)(k0 + kk) * ODIM + h * 64 + o4];
    *(float4*)&sbuf[kk * 68 + o4] = v;
  }
  __syncthreads();
#pragma unroll
  for (int c = 0; c < 2; ++c) {
    const int s = c * 256 + t;
    const int ksl = s >> 8, nt = (s >> 6) & 3, l = s & 63;
    const int col = l & 15, kg = (l >> 4) & 3;
    const int kloc = ksl * 32 + kg * 8;
    const int od = nt * 16 + col;
    bf16x8 o;
#pragma unroll
    for (int u = 0; u < 8; ++u) o[u] = tob(sbuf[(kloc + u) * 68 + od]);
    const size_t off = (((size_t)(h * 4 + nt) * 16 + kb * 2 + ksl) * 64 + l) * 8;
    *(bf16x8*)&Bf[off] = o;
  }
}

// ---------------------------------------------------------------------------
// gemm_fused: grid (64, 8), 256 thr = 4 waves; block = 32 m-rows x head h.
// ---------------------------------------------------------------------------
__global__ __launch_bounds__(256) void gemm_fused(
    const short* __restrict__ Xf, const short* __restrict__ Bf,
    const float* __restrict__ a, short* __restrict__ WhF,
    float2* __restrict__ esrcp, u32* __restrict__ edstp) {
  __shared__ float pbuf[4 * 4 * 64 * 4];  // 16 KB
  const int t = threadIdx.x;
  const int lane = t & 63, w = t >> 6;
  const int col = lane & 15, kgrp = lane >> 4;
  const int bx = blockIdx.x;
  const int h = blockIdx.y;
  const int i0 = bx * 32;

  {
    const int mtg = bx * 2 + (w & 1);  // global 16-row m-tile
    const int kh = w >> 1;             // k-half
    const short* ax = Xf + (size_t)mtg * 8192;
    const short* bxp = Bf + (size_t)h * 32768;

    f32x4 acc1[4] = {};
#pragma unroll
    for (int k2 = 0; k2 < 8; ++k2) {
      const int ks = kh * 8 + k2;
      const bf16x8 af = *(const bf16x8*)&ax[(ks * 64 + lane) * 8];
#pragma unroll
      for (int nt = 0; nt < 4; ++nt) {
        const bf16x8 bf = *(const bf16x8*)&bxp[((nt * 16 + ks) * 64 + lane) * 8];
        acc1[nt] = __builtin_amdgcn_mfma_f32_16x16x32_bf16(af, bf, acc1[nt], 0, 0, 0);
      }
    }
#pragma unroll
    for (int nt = 0; nt < 4; ++nt)
      *(f32x4*)&pbuf[((w * 4 + nt) * 64 + lane) * 4] = acc1[nt];
  }
  __syncthreads();

  if (w < 2) {
    f32x4 acc[4];
#pragma unroll
    for (int nt = 0; nt < 4; ++nt) {
      const f32x4 p0 = *(const f32x4*)&pbuf[((w * 4 + nt) * 64 + lane) * 4];
      const f32x4 p1 = *(const f32x4*)&pbuf[(((w + 2) * 4 + nt) * 64 + lane) * 4];
      acc[nt] = p0 + p1;
    }
    float asv[4], adv[4];
#pragma unroll
    for (int nt = 0; nt < 4; ++nt) {
      asv[nt] = a[nt * 16 + col];
      adv[nt] = a[64 + nt * 16 + col];
    }
    float ps[4], pd[4];
#pragma unroll
    for (int r = 0; r < 4; ++r) {
      float s1 = 0.f, s2 = 0.f;
#pragma unroll
      for (int nt = 0; nt < 4; ++nt) {
        s1 += acc[nt][r] * asv[nt];
        s2 += acc[nt][r] * adv[nt];
      }
      ps[r] = s1;
      pd[r] = s2;
    }
#pragma unroll
    for (int off = 1; off <= 8; off <<= 1) {
#pragma unroll
      for (int r = 0; r < 4; ++r) {
        ps[r] += __shfl_xor(ps[r], off);
        pd[r] += __shfl_xor(pd[r], off);
      }
    }
    {
      const size_t tbase = ((size_t)h * 32 + (bx >> 1)) * 4096;
      const int lp = (w * 2 + (kgrp >> 1)) * 16 + col;
      const int u0 = (kgrp & 1) * 4;
      const int slot_ks = bx & 1;
#pragma unroll
      for (int nt = 0; nt < 4; ++nt) {
        bf16x4 o;
#pragma unroll
        for (int r = 0; r < 4; ++r) o[r] = tob(acc[nt][r]);
        *(bf16x4*)&WhF[tbase + (size_t)(nt * 2 + slot_ks) * 512 + lp * 8 + u0] = o;
      }
    }
    if (col == 0) {
      const int mbase = i0 + w * 16 + kgrp * 4;
#pragma unroll
      for (int r = 0; r < 4; ++r) {
        const int n = mbase + r;
        esrcp[h * NN + n] = make_float2(__expf(ps[r]), __expf(NEG * ps[r]));
        const u32 lo = (u32)(unsigned short)tob(__expf(pd[r]));
        const u32 hi = (u32)(unsigned short)tob(__expf(NEG * pd[r]));
        edstp[h * NN + n] = (hi << 16) | lo;
      }
    }
  }
}

// ---------------------------------------------------------------------------
// attn_skel: ABLATION — R13 attn with p-gen and ALL MFMAs deleted. Staging
// DMAs, vmcnt waits, s_barriers, asm ds_reads intact; results kept live via
// asm sink (rule #17). Writes nothing. Measures the memory+sync skeleton.
// ---------------------------------------------------------------------------
__global__ __launch_bounds__(512, 4) void attn_skel(
    const short* __restrict__ WhF, const unsigned char* __restrict__ adjbits,
    const float2* __restrict__ esrcp, const u32* __restrict__ edstp) {
  extern __shared__ __align__(16) char smem[];  // 4 jq x 18432 B = 73728 B
  const int t = threadIdx.x;
  const int lane = t & 63;
  const int wid = t >> 6;
  const int jq = wid & 3;
  const int mh = wid >> 2;
  const int col = lane & 15;
  const int kgrp = lane >> 4;
  const int h = blockIdx.y;
  const int i0 = blockIdx.x * 32;
  const int irow = i0 + mh * 16;

  char* qbase = smem + jq * 18432;
  char* dbuf = qbase;
  char* elds = qbase + 16384;

  const short* tb = WhF + ((size_t)h * 32 + jq * 8) * 4096;
  const int jb = jq * 512;

  const float2 e0 = esrcp[h * NN + irow + col];
  u64 aw[8];
  {
    const unsigned char* rb = adjbits + (size_t)(irow + col) * (NN / 8) + jq * 64;
#pragma unroll
    for (int q = 0; q < 4; ++q) {
      const uint4 v = *(const uint4*)(rb + q * 16);
      aw[q * 2] = (u64)v.x | ((u64)v.y << 32);
      aw[q * 2 + 1] = (u64)v.z | ((u64)v.w << 32);
    }
  }
  // keep scalar loads alive without consuming them
  asm volatile("" ::"v"(e0.x), "v"(e0.y), "v"(aw[0]), "v"(aw[1]), "v"(aw[2]),
               "v"(aw[3]), "v"(aw[4]), "v"(aw[5]), "v"(aw[6]), "v"(aw[7]));

  const u32 lread = to_lds(dbuf) + (u32)lane * 16u;
  const u32 eread = to_lds(elds) + (u32)kgrp * 32u;

  {
    gl_lds16(edstp + h * NN + jb + mh * 256 + lane * 4, elds + mh * 1024);
#pragma unroll
    for (int s = 0; s < 4; ++s) {
      const int slot = mh * 4 + s;
      gl_lds16(tb + slot * 512 + lane * 8, dbuf + slot * 1024);
    }
  }

#pragma unroll
  for (int tt = 0; tt < 8; ++tt) {
    const int cur = tt & 1, nxt = cur ^ 1;

    if (tt < 7) {
      const short* g = tb + (size_t)(tt + 1) * 4096;
      char* sb = dbuf + nxt * 8192;
#pragma unroll
      for (int s = 0; s < 4; ++s) {
        const int slot = mh * 4 + s;
        gl_lds16(g + slot * 512 + lane * 8, sb + slot * 1024);
      }
      asm volatile("s_waitcnt vmcnt(4)" ::: "memory");
    } else {
      asm volatile("s_waitcnt vmcnt(0)" ::: "memory");
    }
    __builtin_amdgcn_sched_barrier(0);
    __builtin_amdgcn_s_barrier();

    const u32 abuf = lread + (u32)(cur * 8192);
    bf16x8 b0, b1, b2, b3, b4, b5, b6, b7;
    DSR(b0, abuf, "0");
    DSR(b1, abuf, "1024");
    DSR(b2, abuf, "2048");
    DSR(b3, abuf, "3072");
    DSR(b4, abuf, "4096");
    DSR(b5, abuf, "5120");
    DSR(b6, abuf, "6144");
    DSR(b7, abuf, "7168");
    u32x4 eq[4];
    switch (tt) {
      case 0: DSR(eq[0], eread, "0");    DSR(eq[1], eread, "16");   DSR(eq[2], eread, "128");  DSR(eq[3], eread, "144");  break;
      case 1: DSR(eq[0], eread, "256");  DSR(eq[1], eread, "272");  DSR(eq[2], eread, "384");  DSR(eq[3], eread, "400");  break;
      case 2: DSR(eq[0], eread, "512");  DSR(eq[1], eread, "528");  DSR(eq[2], eread, "640");  DSR(eq[3], eread, "656");  break;
      case 3: DSR(eq[0], eread, "768");  DSR(eq[1], eread, "784");  DSR(eq[2], eread, "896");  DSR(eq[3], eread, "912");  break;
      case 4: DSR(eq[0], eread, "1024"); DSR(eq[1], eread, "1040"); DSR(eq[2], eread, "1152"); DSR(eq[3], eread, "1168"); break;
      case 5: DSR(eq[0], eread, "1280"); DSR(eq[1], eread, "1296"); DSR(eq[2], eread, "1408"); DSR(eq[3], eread, "1424"); break;
      case 6: DSR(eq[0], eread, "1536"); DSR(eq[1], eread, "1552"); DSR(eq[2], eread, "1664"); DSR(eq[3], eread, "1680"); break;
      default:DSR(eq[0], eread, "1792"); DSR(eq[1], eread, "1808"); DSR(eq[2], eread, "1920"); DSR(eq[3], eread, "1936"); break;
    }
    asm volatile("s_waitcnt lgkmcnt(0)" ::: "memory");
    __builtin_amdgcn_sched_barrier(0);

    // sink: keep all LDS reads live, no compute
    asm volatile("" ::"v"(b0), "v"(b1), "v"(b2), "v"(b3), "v"(b4), "v"(b5),
                 "v"(b6), "v"(b7), "v"(eq[0]), "v"(eq[1]), "v"(eq[2]),
                 "v"(eq[3]));

    __builtin_amdgcn_s_barrier();
  }
}

// ---------------------------------------------------------------------------
// attn_mfma: identical to round 13.
// ---------------------------------------------------------------------------
__global__ __launch_bounds__(512, 4) void attn_mfma(
    const short* __restrict__ WhF, const unsigned char* __restrict__ adjbits,
    const float2* __restrict__ esrcp, const u32* __restrict__ edstp,
    float* __restrict__ out) {
  extern __shared__ __align__(16) char smem[];  // 4 jq x 18432 B = 73728 B
  const int t = threadIdx.x;
  const int lane = t & 63;
  const int wid = t >> 6;
  const int jq = wid & 3;
  const int mh = wid >> 2;
  const int col = lane & 15, kgrp = lane >> 4;
  const int h = blockIdx.y;
  const int i0 = blockIdx.x * 32;
  const int irow = i0 + mh * 16;

  char* qbase = smem + jq * 18432;
  char* dbuf = qbase;          // [2][8192] B-fragments (shared by the pair)
  char* elds = qbase + 16384;  // 2048 B edstp

  const short* tb = WhF + ((size_t)h * 32 + jq * 8) * 4096;
  const int jb = jq * 512;

  const float2 e0 = esrcp[h * NN + irow + col];
  const float A0 = e0.x, C0 = e0.y;

  u64 aw[8];
  {
    const unsigned char* rb = adjbits + (size_t)(irow + col) * (NN / 8) + jq * 64;
#pragma unroll
    for (int q = 0; q < 4; ++q) {
      const uint4 v = *(const uint4*)(rb + q * 16);
      aw[q * 2] = (u64)v.x | ((u64)v.y << 32);
      aw[q * 2 + 1] = (u64)v.z | ((u64)v.w << 32);
    }
  }

  bf16x8 ones;
#pragma unroll
  for (int u = 0; u < 8; ++u) ones[u] = (short)0x3F80;

  f32x4 acc[4] = {};
  f32x4 accd = {};

  const u32 lread = to_lds(dbuf) + (u32)lane * 16u;
  const u32 eread = to_lds(elds) + (u32)kgrp * 32u;

  {
    gl_lds16(edstp + h * NN + jb + mh * 256 + lane * 4, elds + mh * 1024);
#pragma unroll
    for (int s = 0; s < 4; ++s) {
      const int slot = mh * 4 + s;
      gl_lds16(tb + slot * 512 + lane * 8, dbuf + slot * 1024);
    }
  }

#pragma unroll
  for (int tt = 0; tt < 8; ++tt) {
    const int cur = tt & 1, nxt = cur ^ 1;

    if (tt < 7) {
      const short* g = tb + (size_t)(tt + 1) * 4096;
      char* sb = dbuf + nxt * 8192;
#pragma unroll
      for (int s = 0; s < 4; ++s) {
        const int slot = mh * 4 + s;
        gl_lds16(g + slot * 512 + lane * 8, sb + slot * 1024);
      }
      asm volatile("s_waitcnt vmcnt(4)" ::: "memory");
    } else {
      asm volatile("s_waitcnt vmcnt(0)" ::: "memory");
    }
    __builtin_amdgcn_sched_barrier(0);
    __builtin_amdgcn_s_barrier();  // pair-join: partner's slots also landed

    const u32 abuf = lread + (u32)(cur * 8192);
    bf16x8 b0, b1, b2, b3, b4, b5, b6, b7;
    DSR(b0, abuf, "0");
    DSR(b1, abuf, "1024");
    DSR(b2, abuf, "2048");
    DSR(b3, abuf, "3072");
    DSR(b4, abuf, "4096");
    DSR(b5, abuf, "5120");
    DSR(b6, abuf, "6144");
    DSR(b7, abuf, "7168");
    u32x4 eq[4];
    switch (tt) {  // compile-time offsets (tt unrolled)
      case 0: DSR(eq[0], eread, "0");    DSR(eq[1], eread, "16");   DSR(eq[2], eread, "128");  DSR(eq[3], eread, "144");  break;
      case 1: DSR(eq[0], eread, "256");  DSR(eq[1], eread, "272");  DSR(eq[2], eread, "384");  DSR(eq[3], eread, "400");  break;
      case 2: DSR(eq[0], eread, "512");  DSR(eq[1], eread, "528");  DSR(eq[2], eread, "640");  DSR(eq[3], eread, "656");  break;
      case 3: DSR(eq[0], eread, "768");  DSR(eq[1], eread, "784");  DSR(eq[2], eread, "896");  DSR(eq[3], eread, "912");  break;
      case 4: DSR(eq[0], eread, "1024"); DSR(eq[1], eread, "1040"); DSR(eq[2], eread, "1152"); DSR(eq[3], eread, "1168"); break;
      case 5: DSR(eq[0], eread, "1280"); DSR(eq[1], eread, "1296"); DSR(eq[2], eread, "1408"); DSR(eq[3], eread, "1424"); break;
      case 6: DSR(eq[0], eread, "1536"); DSR(eq[1], eread, "1552"); DSR(eq[2], eread, "1664"); DSR(eq[3], eread, "1680"); break;
      default:DSR(eq[0], eread, "1792"); DSR(eq[1], eread, "1808"); DSR(eq[2], eread, "1920"); DSR(eq[3], eread, "1936"); break;
    }
    asm volatile("s_waitcnt lgkmcnt(0)" ::: "memory");
    __builtin_amdgcn_sched_barrier(0);

    bf16x8 af[2];
#pragma unroll
    for (int ks = 0; ks < 2; ++ks) {
      const u32 mb = (u32)(aw[tt] >> ((ks * 4 + kgrp) * 8)) & 0xffu;
      const u32x4 q0 = eq[ks * 2], q1 = eq[ks * 2 + 1];
      const u32 uw[8] = {q0[0], q0[1], q0[2], q0[3], q1[0], q1[1], q1[2], q1[3]};
#pragma unroll
      for (int u2 = 0; u2 < 8; ++u2) {
        const float B = __uint_as_float(uw[u2] << 16);
        const float D = __uint_as_float(uw[u2] & 0xffff0000u);
        float p = fmaxf(A0 * B, C0 * D);
        p = ((mb >> u2) & 1u) ? p : 0.f;
        af[ks][u2] = tob(p);
      }
    }

    __builtin_amdgcn_s_setprio(1);
    accd = __builtin_amdgcn_mfma_f32_16x16x32_bf16(af[0], ones, accd, 0, 0, 0);
    accd = __builtin_amdgcn_mfma_f32_16x16x32_bf16(af[1], ones, accd, 0, 0, 0);
    acc[0] = __builtin_amdgcn_mfma_f32_16x16x32_bf16(af[0], b0, acc[0], 0, 0, 0);
    acc[0] = __builtin_amdgcn_mfma_f32_16x16x32_bf16(af[1], b1, acc[0], 0, 0, 0);
    acc[1] = __builtin_amdgcn_mfma_f32_16x16x32_bf16(af[0], b2, acc[1], 0, 0, 0);
    acc[1] = __builtin_amdgcn_mfma_f32_16x16x32_bf16(af[1], b3, acc[1], 0, 0, 0);
    acc[2] = __builtin_amdgcn_mfma_f32_16x16x32_bf16(af[0], b4, acc[2], 0, 0, 0);
    acc[2] = __builtin_amdgcn_mfma_f32_16x16x32_bf16(af[1], b5, acc[2], 0, 0, 0);
    acc[3] = __builtin_amdgcn_mfma_f32_16x16x32_bf16(af[0], b6, acc[3], 0, 0, 0);
    acc[3] = __builtin_amdgcn_mfma_f32_16x16x32_bf16(af[1], b7, acc[3], 0, 0, 0);
    __builtin_amdgcn_s_setprio(0);

    __builtin_amdgcn_s_barrier();  // pair done reading cur -> safe to refill
  }

  // ---- cross-jq reduce (aliases dead staging LDS) ----
  __syncthreads();
  float* red = (float*)smem;  // [2 mh][4 jq][16 row][66]; den at col 64
  float* rw = red + (size_t)((mh * 4 + jq) * 16) * 66;
#pragma unroll
  for (int nt = 0; nt < 4; ++nt)
#pragma unroll
    for (int r = 0; r < 4; ++r)
      rw[(kgrp * 4 + r) * 66 + nt * 16 + col] = acc[nt][r];
  if (col == 0) {
#pragma unroll
    for (int r = 0; r < 4; ++r) rw[(kgrp * 4 + r) * 66 + 64] = accd[r];
  }
  __syncthreads();

  const int d = t & 63, idx = t >> 6;
#pragma unroll
  for (int rr = 0; rr < 4; ++rr) {
    const int row = rr * 8 + idx;
    const int mh2 = row >> 4, r16 = row & 15;
    float v = 0.f, dd = 0.f;
#pragma unroll
    for (int q = 0; q < 4; ++q) {
      const float* rb = red + (size_t)((mh2 * 4 + q) * 16 + r16) * 66;
      v += rb[d];
      dd += rb[64];
    }
    out[(size_t)(i0 + row) * ODIM + h * HD + d] = v / dd;
  }
}

// ---------------------------------------------------------------------------
// ABLATION ROUND: prep, gemm, attn_skel x3 (memory+sync skeleton, writes
// nothing), then the unmodified R13 attn (sole writer of out). skel + gap =
// (T - 34.9) / 3 identifies whether attn is memory/sync-bound or
// compute/serialization-bound. Round 17 acts on the answer.
// ---------------------------------------------------------------------------
extern "C" void kernel_launch(void* const* d_in, const int* in_sizes, int n_in,
                              void* d_out, int out_size, void* d_ws,
                              size_t ws_size, hipStream_t stream) {
  const float* x = (const float*)d_in[0];
  const int* adj = (const int*)d_in[1];
  const float* W = (const float*)d_in[2];
  const float* a = (const float*)d_in[3];
  float* out = (float*)d_out;

  char* ws = (char*)d_ws;
  short* WhF = (short*)ws;                                    // 2 MB
  short* Xf = (short*)(ws + (2 << 20));                       // 2 MB
  short* Bf = (short*)(ws + (4 << 20));                       // 512 KB
  unsigned short* bits =
      (unsigned short*)(ws + (4 << 20) + (512 << 10));        // 512 KB
  float2* esrcp = (float2*)(ws + (5 << 20));                  // 128 KB
  u32* edstp = (u32*)(ws + (5 << 20) + (128 << 10));          // 64 KB

  prep<<<1216, 256, 0, stream>>>(x, W, adj, Xf, Bf, bits);
  gemm_fused<<<dim3(64, 8), 256, 0, stream>>>(Xf, Bf, a, WhF, esrcp, edstp);
  attn_skel<<<dim3(64, 8), 512, 73728, stream>>>(
      WhF, (const unsigned char*)bits, esrcp, edstp);
  attn_skel<<<dim3(64, 8), 512, 73728, stream>>>(
      WhF, (const unsigned char*)bits, esrcp, edstp);
  attn_skel<<<dim3(64, 8), 512, 73728, stream>>>(
      WhF, (const unsigned char*)bits, esrcp, edstp);
  attn_mfma<<<dim3(64, 8), 512, 73728, stream>>>(
      WhF, (const unsigned char*)bits, esrcp, edstp, out);
}

// Round 17
// 38.557 us; speedup vs baseline: 2.1642x; 1.5312x over previous
//
#include <hip/hip_runtime.h>
#include <hip/hip_bf16.h>

#define NN 2048
#define KD 512
#define ODIM 512
#define NHEAD 8
#define HD 64
#define NEG 0.2f

typedef float f32x4 __attribute__((ext_vector_type(4)));
typedef short bf16x8 __attribute__((ext_vector_type(8)));
typedef short bf16x4 __attribute__((ext_vector_type(4)));
typedef unsigned int u32x4 __attribute__((ext_vector_type(4)));
typedef unsigned long long u64;
typedef unsigned int u32;

__device__ __forceinline__ short tob(float f) {
  __hip_bfloat16 h = __float2bfloat16(f);
  return *reinterpret_cast<short*>(&h);
}

// async global -> LDS; LDS dest = uniform base + lane*16
__device__ __forceinline__ void gl_lds16(const void* g, void* l) {
  __builtin_amdgcn_global_load_lds(
      (const __attribute__((address_space(1))) u32*)g,
      (__attribute__((address_space(3))) u32*)l, 16, 0, 0);
}

__device__ __forceinline__ u32 to_lds(const void* p) {
  return (u32)(size_t)(const __attribute__((address_space(3))) char*)p;
}

// inline-asm ds_read_b128: opaque to the waitcnt legalizer (no auto drains)
#define DSR(dst, addr, OFFLIT)                      \
  asm volatile("ds_read_b128 %0, %1 offset:" OFFLIT \
               : "=v"(dst)                          \
               : "v"(addr))

// eq reads for tile T (compile-time T; offsets = T*256 + {0,16,128,144})
#define EQREAD(eq, T)                                                         \
  switch (T) {                                                                \
    case 0: DSR(eq[0], eread, "0");    DSR(eq[1], eread, "16");   DSR(eq[2], eread, "128");  DSR(eq[3], eread, "144");  break; \
    case 1: DSR(eq[0], eread, "256");  DSR(eq[1], eread, "272");  DSR(eq[2], eread, "384");  DSR(eq[3], eread, "400");  break; \
    case 2: DSR(eq[0], eread, "512");  DSR(eq[1], eread, "528");  DSR(eq[2], eread, "640");  DSR(eq[3], eread, "656");  break; \
    case 3: DSR(eq[0], eread, "768");  DSR(eq[1], eread, "784");  DSR(eq[2], eread, "896");  DSR(eq[3], eread, "912");  break; \
    case 4: DSR(eq[0], eread, "1024"); DSR(eq[1], eread, "1040"); DSR(eq[2], eread, "1152"); DSR(eq[3], eread, "1168"); break; \
    case 5: DSR(eq[0], eread, "1280"); DSR(eq[1], eread, "1296"); DSR(eq[2], eread, "1408"); DSR(eq[3], eread, "1424"); break; \
    case 6: DSR(eq[0], eread, "1536"); DSR(eq[1], eread, "1552"); DSR(eq[2], eread, "1664"); DSR(eq[3], eread, "1680"); break; \
    default:DSR(eq[0], eread, "1792"); DSR(eq[1], eread, "1808"); DSR(eq[2], eread, "1920"); DSR(eq[3], eread, "1936"); break; \
  }

// p-gen: eq (4x u32x4) + adj word -> A-fragments (no transcendentals)
#define PGEN(dst, EQ, AWV)                                          \
  {                                                                 \
    _Pragma("unroll") for (int ks = 0; ks < 2; ++ks) {              \
      const u32 mb = (u32)((AWV) >> ((ks * 4 + kgrp) * 8)) & 0xffu; \
      const u32x4 q0 = EQ[ks * 2], q1 = EQ[ks * 2 + 1];             \
      const u32 uw[8] = {q0[0], q0[1], q0[2], q0[3],                \
                         q1[0], q1[1], q1[2], q1[3]};               \
      _Pragma("unroll") for (int u2 = 0; u2 < 8; ++u2) {            \
        const float B = __uint_as_float(uw[u2] << 16);              \
        const float D = __uint_as_float(uw[u2] & 0xffff0000u);      \
        float p = fmaxf(A0 * B, C0 * D);                            \
        p = ((mb >> u2) & 1u) ? p : 0.f;                            \
        dst[ks][u2] = tob(p);                                       \
      }                                                             \
    }                                                               \
  }

// ---------------------------------------------------------------------------
// prep: blocks 0..1023   pack adj -> bitmask
//       blocks 1024..1151 Xf: X (f32) -> bf16 in MFMA-A-fragment order
//       blocks 1152..1215 Bf: W (f32) -> bf16 in MFMA-B-fragment order
// ---------------------------------------------------------------------------
__global__ __launch_bounds__(256) void prep(const float* __restrict__ X,
                                            const float* __restrict__ W,
                                            const int* __restrict__ adj,
                                            short* __restrict__ Xf,
                                            short* __restrict__ Bf,
                                            unsigned short* __restrict__ bits) {
  __shared__ float sbuf[16 * 516];
  const int b = blockIdx.x;
  const int t = threadIdx.x;

  if (b < 1024) {  // ---- adj pack ----
    const int T = b * 256 + t;
    const int row = T >> 7, g = T & 127;
    const int* p = adj + (size_t)row * NN + g * 16;
    u32 m = 0;
#pragma unroll
    for (int q = 0; q < 4; ++q) {
      const int4 v = *(const int4*)&p[q * 4];
      m |= (v.x > 0 ? 1u : 0u) << (q * 4);
      m |= (v.y > 0 ? 2u : 0u) << (q * 4);
      m |= (v.z > 0 ? 4u : 0u) << (q * 4);
      m |= (v.w > 0 ? 8u : 0u) << (q * 4);
    }
    bits[T] = (unsigned short)m;
    return;
  }

  if (b < 1024 + 128) {  // ---- X -> Xf ----
    const int xb = b - 1024;
#pragma unroll
    for (int q = 0; q < 8; ++q) {
      const int flat = q * 256 + t;
      const int row = flat >> 7, c4 = flat & 127;
      const float4 v = *(const float4*)&X[(size_t)(xb * 16 + row) * KD + c4 * 4];
      *(float4*)&sbuf[row * 516 + c4 * 4] = v;
    }
    __syncthreads();
#pragma unroll
    for (int c = 0; c < 4; ++c) {
      const int s = c * 256 + t;
      const int l = s & 63;
      const int col = l & 15, kg = (l >> 4) & 3;
      const int k0 = (s >> 6) * 32 + kg * 8;
      bf16x8 o;
#pragma unroll
      for (int u = 0; u < 8; ++u) o[u] = tob(sbuf[col * 516 + k0 + u]);
      *(bf16x8*)&Xf[((size_t)xb * 1024 + s) * 8] = o;
    }
    return;
  }

  // ---- W -> Bf ----
  const int b2 = b - 1152;
  const int kb = b2 & 7, h = b2 >> 3;
  const int k0 = kb * 64;
#pragma unroll
  for (int q = 0; q < 4; ++q) {
    const int flat = q * 256 + t;
    const int kk = flat >> 4, o4 = (flat & 15) * 4;
    const float4 v = *(const float4*)&W[(size_t)(k0 + kk) * ODIM + h * 64 + o4];
    *(float4*)&sbuf[kk * 68 + o4] = v;
  }
  __syncthreads();
#pragma unroll
  for (int c = 0; c < 2; ++c) {
    const int s = c * 256 + t;
    const int ksl = s >> 8, nt = (s >> 6) & 3, l = s & 63;
    const int col = l & 15, kg = (l >> 4) & 3;
    const int kloc = ksl * 32 + kg * 8;
    const int od = nt * 16 + col;
    bf16x8 o;
#pragma unroll
    for (int u = 0; u < 8; ++u) o[u] = tob(sbuf[(kloc + u) * 68 + od]);
    const size_t off = (((size_t)(h * 4 + nt) * 16 + kb * 2 + ksl) * 64 + l) * 8;
    *(bf16x8*)&Bf[off] = o;
  }
}

// ---------------------------------------------------------------------------
// gemm_fused: grid (64, 8), 256 thr = 4 waves; block = 32 m-rows x head h.
// ---------------------------------------------------------------------------
__global__ __launch_bounds__(256) void gemm_fused(
    const short* __restrict__ Xf, const short* __restrict__ Bf,
    const float* __restrict__ a, short* __restrict__ WhF,
    float2* __restrict__ esrcp, u32* __restrict__ edstp) {
  __shared__ float pbuf[4 * 4 * 64 * 4];  // 16 KB
  const int t = threadIdx.x;
  const int lane = t & 63, w = t >> 6;
  const int col = lane & 15, kgrp = lane >> 4;
  const int bx = blockIdx.x;
  const int h = blockIdx.y;
  const int i0 = bx * 32;

  {
    const int mtg = bx * 2 + (w & 1);  // global 16-row m-tile
    const int kh = w >> 1;             // k-half
    const short* ax = Xf + (size_t)mtg * 8192;
    const short* bxp = Bf + (size_t)h * 32768;

    f32x4 acc1[4] = {};
#pragma unroll
    for (int k2 = 0; k2 < 8; ++k2) {
      const int ks = kh * 8 + k2;
      const bf16x8 af = *(const bf16x8*)&ax[(ks * 64 + lane) * 8];
#pragma unroll
      for (int nt = 0; nt < 4; ++nt) {
        const bf16x8 bf = *(const bf16x8*)&bxp[((nt * 16 + ks) * 64 + lane) * 8];
        acc1[nt] = __builtin_amdgcn_mfma_f32_16x16x32_bf16(af, bf, acc1[nt], 0, 0, 0);
      }
    }
#pragma unroll
    for (int nt = 0; nt < 4; ++nt)
      *(f32x4*)&pbuf[((w * 4 + nt) * 64 + lane) * 4] = acc1[nt];
  }
  __syncthreads();

  if (w < 2) {
    f32x4 acc[4];
#pragma unroll
    for (int nt = 0; nt < 4; ++nt) {
      const f32x4 p0 = *(const f32x4*)&pbuf[((w * 4 + nt) * 64 + lane) * 4];
      const f32x4 p1 = *(const f32x4*)&pbuf[(((w + 2) * 4 + nt) * 64 + lane) * 4];
      acc[nt] = p0 + p1;
    }
    float asv[4], adv[4];
#pragma unroll
    for (int nt = 0; nt < 4; ++nt) {
      asv[nt] = a[nt * 16 + col];
      adv[nt] = a[64 + nt * 16 + col];
    }
    float ps[4], pd[4];
#pragma unroll
    for (int r = 0; r < 4; ++r) {
      float s1 = 0.f, s2 = 0.f;
#pragma unroll
      for (int nt = 0; nt < 4; ++nt) {
        s1 += acc[nt][r] * asv[nt];
        s2 += acc[nt][r] * adv[nt];
      }
      ps[r] = s1;
      pd[r] = s2;
    }
#pragma unroll
    for (int off = 1; off <= 8; off <<= 1) {
#pragma unroll
      for (int r = 0; r < 4; ++r) {
        ps[r] += __shfl_xor(ps[r], off);
        pd[r] += __shfl_xor(pd[r], off);
      }
    }
    {
      const size_t tbase = ((size_t)h * 32 + (bx >> 1)) * 4096;
      const int lp = (w * 2 + (kgrp >> 1)) * 16 + col;
      const int u0 = (kgrp & 1) * 4;
      const int slot_ks = bx & 1;
#pragma unroll
      for (int nt = 0; nt < 4; ++nt) {
        bf16x4 o;
#pragma unroll
        for (int r = 0; r < 4; ++r) o[r] = tob(acc[nt][r]);
        *(bf16x4*)&WhF[tbase + (size_t)(nt * 2 + slot_ks) * 512 + lp * 8 + u0] = o;
      }
    }
    if (col == 0) {
      const int mbase = i0 + w * 16 + kgrp * 4;
#pragma unroll
      for (int r = 0; r < 4; ++r) {
        const int n = mbase + r;
        esrcp[h * NN + n] = make_float2(__expf(ps[r]), __expf(NEG * ps[r]));
        const u32 lo = (u32)(unsigned short)tob(__expf(pd[r]));
        const u32 hi = (u32)(unsigned short)tob(__expf(NEG * pd[r]));
        edstp[h * NN + n] = (hi << 16) | lo;
      }
    }
  }
}

// ---------------------------------------------------------------------------
// attn_mfma: R13 structure + SOFTWARE-PIPELINED A-FRAGMENTS. p-gen depends
// only on edstp (LDS, staged once) + adj/esrcp (registers), NOT on per-tile
// staging. So: af[tile 0] computed in the prologue; at tile tt, eq reads for
// tile tt+1 are issued FIRST, lgkmcnt(8) (eq done, b in flight), p-gen for
// tt+1 OVERLAPS the b-read latency, then lgkmcnt(0) -> MFMA with the
// precomputed af[tt]. p-gen leaves the barrier-to-barrier critical path.
// ---------------------------------------------------------------------------
__global__ __launch_bounds__(512, 4) void attn_mfma(
    const short* __restrict__ WhF, const unsigned char* __restrict__ adjbits,
    const float2* __restrict__ esrcp, const u32* __restrict__ edstp,
    float* __restrict__ out) {
  extern __shared__ __align__(16) char smem[];  // 4 jq x 18432 B = 73728 B
  const int t = threadIdx.x;
  const int lane = t & 63;
  const int wid = t >> 6;
  const int jq = wid & 3;
  const int mh = wid >> 2;
  const int col = lane & 15, kgrp = lane >> 4;
  const int h = blockIdx.y;
  const int i0 = blockIdx.x * 32;
  const int irow = i0 + mh * 16;

  char* qbase = smem + jq * 18432;
  char* dbuf = qbase;          // [2][8192] B-fragments (shared by the pair)
  char* elds = qbase + 16384;  // 2048 B edstp

  const short* tb = WhF + ((size_t)h * 32 + jq * 8) * 4096;
  const int jb = jq * 512;

  const float2 e0 = esrcp[h * NN + irow + col];
  const float A0 = e0.x, C0 = e0.y;

  u64 aw[8];
  {
    const unsigned char* rb = adjbits + (size_t)(irow + col) * (NN / 8) + jq * 64;
#pragma unroll
    for (int q = 0; q < 4; ++q) {
      const uint4 v = *(const uint4*)(rb + q * 16);
      aw[q * 2] = (u64)v.x | ((u64)v.y << 32);
      aw[q * 2 + 1] = (u64)v.z | ((u64)v.w << 32);
    }
  }

  bf16x8 ones;
#pragma unroll
  for (int u = 0; u < 8; ++u) ones[u] = (short)0x3F80;

  f32x4 acc[4] = {};
  f32x4 accd = {};

  const u32 lread = to_lds(dbuf) + (u32)lane * 16u;
  const u32 eread = to_lds(elds) + (u32)kgrp * 32u;

  // A-fragment pipeline: af[tt&1] consumed at tile tt, af[(tt+1)&1] produced.
  bf16x8 af[2][2];

  // ---- prologue: stage edstp half + tile-0 slots; drain; block-join;
  //      then p-gen af[0] (tile 0) from LDS-resident edstp ----
  {
    gl_lds16(edstp + h * NN + jb + mh * 256 + lane * 4, elds + mh * 1024);
#pragma unroll
    for (int s = 0; s < 4; ++s) {
      const int slot = mh * 4 + s;
      gl_lds16(tb + slot * 512 + lane * 8, dbuf + slot * 1024);
    }
  }
  asm volatile("s_waitcnt vmcnt(0)" ::: "memory");
  __builtin_amdgcn_sched_barrier(0);
  __builtin_amdgcn_s_barrier();  // both elds halves + tile-0 slots visible
  {
    u32x4 eq[4];
    EQREAD(eq, 0);
    asm volatile("s_waitcnt lgkmcnt(0)" ::: "memory");
    __builtin_amdgcn_sched_barrier(0);
    PGEN(af[0], eq, aw[0]);
  }

#pragma unroll
  for (int tt = 0; tt < 8; ++tt) {
    const int cur = tt & 1, nxt = cur ^ 1;

    // ---- issue this wave's 4 slots of tile tt+1, wait own tile-tt loads ----
    if (tt < 7) {
      const short* g = tb + (size_t)(tt + 1) * 4096;
      char* sb = dbuf + nxt * 8192;
#pragma unroll
      for (int s = 0; s < 4; ++s) {
        const int slot = mh * 4 + s;
        gl_lds16(g + slot * 512 + lane * 8, sb + slot * 1024);
      }
      asm volatile("s_waitcnt vmcnt(4)" ::: "memory");
    } else {
      asm volatile("s_waitcnt vmcnt(0)" ::: "memory");
    }
    __builtin_amdgcn_sched_barrier(0);
    __builtin_amdgcn_s_barrier();  // pair-join: partner's slots also landed

    // ---- eq reads for NEXT tile first, then b reads for CURRENT tile ----
    u32x4 eqn[4];
    if (tt < 7) {
      EQREAD(eqn, tt + 1);
    }
    const u32 abuf = lread + (u32)(cur * 8192);
    bf16x8 b0, b1, b2, b3, b4, b5, b6, b7;
    DSR(b0, abuf, "0");
    DSR(b1, abuf, "1024");
    DSR(b2, abuf, "2048");
    DSR(b3, abuf, "3072");
    DSR(b4, abuf, "4096");
    DSR(b5, abuf, "5120");
    DSR(b6, abuf, "6144");
    DSR(b7, abuf, "7168");

    // ---- p-gen for tile tt+1 overlaps b-read latency ----
    if (tt < 7) {
      asm volatile("s_waitcnt lgkmcnt(8)" ::: "memory");  // eq done, b in flight
      __builtin_amdgcn_sched_barrier(0);
      PGEN(af[nxt], eqn, aw[tt + 1]);
    }

    asm volatile("s_waitcnt lgkmcnt(0)" ::: "memory");  // b done
    __builtin_amdgcn_sched_barrier(0);

    // ---- MFMAs with precomputed af[cur] ----
    __builtin_amdgcn_s_setprio(1);
    accd = __builtin_amdgcn_mfma_f32_16x16x32_bf16(af[cur][0], ones, accd, 0, 0, 0);
    accd = __builtin_amdgcn_mfma_f32_16x16x32_bf16(af[cur][1], ones, accd, 0, 0, 0);
    acc[0] = __builtin_amdgcn_mfma_f32_16x16x32_bf16(af[cur][0], b0, acc[0], 0, 0, 0);
    acc[0] = __builtin_amdgcn_mfma_f32_16x16x32_bf16(af[cur][1], b1, acc[0], 0, 0, 0);
    acc[1] = __builtin_amdgcn_mfma_f32_16x16x32_bf16(af[cur][0], b2, acc[1], 0, 0, 0);
    acc[1] = __builtin_amdgcn_mfma_f32_16x16x32_bf16(af[cur][1], b3, acc[1], 0, 0, 0);
    acc[2] = __builtin_amdgcn_mfma_f32_16x16x32_bf16(af[cur][0], b4, acc[2], 0, 0, 0);
    acc[2] = __builtin_amdgcn_mfma_f32_16x16x32_bf16(af[cur][1], b5, acc[2], 0, 0, 0);
    acc[3] = __builtin_amdgcn_mfma_f32_16x16x32_bf16(af[cur][0], b6, acc[3], 0, 0, 0);
    acc[3] = __builtin_amdgcn_mfma_f32_16x16x32_bf16(af[cur][1], b7, acc[3], 0, 0, 0);
    __builtin_amdgcn_s_setprio(0);

    __builtin_amdgcn_s_barrier();  // pair done reading cur -> safe to refill
  }

  // ---- cross-jq reduce (aliases dead staging LDS) ----
  __syncthreads();
  float* red = (float*)smem;  // [2 mh][4 jq][16 row][66]; den at col 64
  float* rw = red + (size_t)((mh * 4 + jq) * 16) * 66;
#pragma unroll
  for (int nt = 0; nt < 4; ++nt)
#pragma unroll
    for (int r = 0; r < 4; ++r)
      rw[(kgrp * 4 + r) * 66 + nt * 16 + col] = acc[nt][r];
  if (col == 0) {
#pragma unroll
    for (int r = 0; r < 4; ++r) rw[(kgrp * 4 + r) * 66 + 64] = accd[r];
  }
  __syncthreads();

  const int d = t & 63, idx = t >> 6;
#pragma unroll
  for (int rr = 0; rr < 4; ++rr) {
    const int row = rr * 8 + idx;
    const int mh2 = row >> 4, r16 = row & 15;
    float v = 0.f, dd = 0.f;
#pragma unroll
    for (int q = 0; q < 4; ++q) {
      const float* rb = red + (size_t)((mh2 * 4 + q) * 16 + r16) * 66;
      v += rb[d];
      dd += rb[64];
    }
    out[(size_t)(i0 + row) * ODIM + h * HD + d] = v / dd;
  }
}

// ---------------------------------------------------------------------------
extern "C" void kernel_launch(void* const* d_in, const int* in_sizes, int n_in,
                              void* d_out, int out_size, void* d_ws,
                              size_t ws_size, hipStream_t stream) {
  const float* x = (const float*)d_in[0];
  const int* adj = (const int*)d_in[1];
  const float* W = (const float*)d_in[2];
  const float* a = (const float*)d_in[3];
  float* out = (float*)d_out;

  char* ws = (char*)d_ws;
  short* WhF = (short*)ws;                                    // 2 MB
  short* Xf = (short*)(ws + (2 << 20));                       // 2 MB
  short* Bf = (short*)(ws + (4 << 20));                       // 512 KB
  unsigned short* bits =
      (unsigned short*)(ws + (4 << 20) + (512 << 10));        // 512 KB
  float2* esrcp = (float2*)(ws + (5 << 20));                  // 128 KB
  u32* edstp = (u32*)(ws + (5 << 20) + (128 << 10));          // 64 KB

  prep<<<1216, 256, 0, stream>>>(x, W, adj, Xf, Bf, bits);
  gemm_fused<<<dim3(64, 8), 256, 0, stream>>>(Xf, Bf, a, WhF, esrcp, edstp);
  attn_mfma<<<dim3(64, 8), 512, 73728, stream>>>(
      WhF, (const unsigned char*)bits, esrcp, edstp, out);
}

// Round 18
// 33.947 us; speedup vs baseline: 2.4580x; 1.1358x over previous
//
#include <hip/hip_runtime.h>
#include <hip/hip_bf16.h>

#define NN 2048
#define KD 512
#define ODIM 512
#define NHEAD 8
#define HD 64
#define NEG 0.2f

typedef float f32x4 __attribute__((ext_vector_type(4)));
typedef short bf16x8 __attribute__((ext_vector_type(8)));
typedef short bf16x4 __attribute__((ext_vector_type(4)));
typedef unsigned int u32x4 __attribute__((ext_vector_type(4)));
typedef unsigned long long u64;
typedef unsigned int u32;

typedef union {
  u32x4 w;
  bf16x8 h;
} pk8;

__device__ __forceinline__ short tob(float f) {
  __hip_bfloat16 h = __float2bfloat16(f);
  return *reinterpret_cast<short*>(&h);
}

// async global -> LDS; LDS dest = uniform base + lane*16
__device__ __forceinline__ void gl_lds16(const void* g, void* l) {
  __builtin_amdgcn_global_load_lds(
      (const __attribute__((address_space(1))) u32*)g,
      (__attribute__((address_space(3))) u32*)l, 16, 0, 0);
}

__device__ __forceinline__ u32 to_lds(const void* p) {
  return (u32)(size_t)(const __attribute__((address_space(3))) char*)p;
}

// inline-asm ds_read_b128: opaque to the waitcnt legalizer (no auto drains)
#define DSR(dst, addr, OFFLIT)                      \
  asm volatile("ds_read_b128 %0, %1 offset:" OFFLIT \
               : "=v"(dst)                          \
               : "v"(addr))

// eq reads for tile T (compile-time T; offsets = T*256 + {0,16,128,144})
#define EQREAD(eq, T)                                                         \
  switch (T) {                                                                \
    case 0: DSR(eq[0], eread, "0");    DSR(eq[1], eread, "16");   DSR(eq[2], eread, "128");  DSR(eq[3], eread, "144");  break; \
    case 1: DSR(eq[0], eread, "256");  DSR(eq[1], eread, "272");  DSR(eq[2], eread, "384");  DSR(eq[3], eread, "400");  break; \
    case 2: DSR(eq[0], eread, "512");  DSR(eq[1], eread, "528");  DSR(eq[2], eread, "640");  DSR(eq[3], eread, "656");  break; \
    case 3: DSR(eq[0], eread, "768");  DSR(eq[1], eread, "784");  DSR(eq[2], eread, "896");  DSR(eq[3], eread, "912");  break; \
    case 4: DSR(eq[0], eread, "1024"); DSR(eq[1], eread, "1040"); DSR(eq[2], eread, "1152"); DSR(eq[3], eread, "1168"); break; \
    case 5: DSR(eq[0], eread, "1280"); DSR(eq[1], eread, "1296"); DSR(eq[2], eread, "1408"); DSR(eq[3], eread, "1424"); break; \
    case 6: DSR(eq[0], eread, "1536"); DSR(eq[1], eread, "1552"); DSR(eq[2], eread, "1664"); DSR(eq[3], eread, "1680"); break; \
    default:DSR(eq[0], eread, "1792"); DSR(eq[1], eread, "1808"); DSR(eq[2], eread, "1920"); DSR(eq[3], eread, "1936"); break; \
  }

// p-gen with v_cvt_pk_bf16_f32 convert+pack (1 op per 2 elems, RNE)
#define PGEN_PK(dstv, EQ, AWV)                                      \
  {                                                                 \
    _Pragma("unroll") for (int ks = 0; ks < 2; ++ks) {              \
      const u32 mb = (u32)((AWV) >> ((ks * 4 + kgrp) * 8)) & 0xffu; \
      const u32x4 q0 = EQ[ks * 2], q1 = EQ[ks * 2 + 1];             \
      const u32 uw[8] = {q0[0], q0[1], q0[2], q0[3],                \
                         q1[0], q1[1], q1[2], q1[3]};               \
      float pv[8];                                                  \
      _Pragma("unroll") for (int u2 = 0; u2 < 8; ++u2) {            \
        const float B = __uint_as_float(uw[u2] << 16);              \
        const float D = __uint_as_float(uw[u2] & 0xffff0000u);      \
        const float p = fmaxf(A0 * B, C0 * D);                      \
        pv[u2] = ((mb >> u2) & 1u) ? p : 0.f;                       \
      }                                                             \
      pk8 r;                                                        \
      _Pragma("unroll") for (int w2 = 0; w2 < 4; ++w2) {            \
        u32 rr;                                                     \
        asm("v_cvt_pk_bf16_f32 %0, %1, %2"                          \
            : "=v"(rr)                                              \
            : "v"(pv[w2 * 2]), "v"(pv[w2 * 2 + 1]));                \
        r.w[w2] = rr;                                               \
      }                                                             \
      dstv[ks] = r.h;                                               \
    }                                                               \
  }

// ---------------------------------------------------------------------------
// prep: blocks 0..1023   pack adj -> bitmask
//       blocks 1024..1151 Xf: X (f32) -> bf16 in MFMA-A-fragment order
//       blocks 1152..1215 Bf: W (f32) -> bf16 in MFMA-B-fragment order
// ---------------------------------------------------------------------------
__global__ __launch_bounds__(256) void prep(const float* __restrict__ X,
                                            const float* __restrict__ W,
                                            const int* __restrict__ adj,
                                            short* __restrict__ Xf,
                                            short* __restrict__ Bf,
                                            unsigned short* __restrict__ bits) {
  __shared__ float sbuf[16 * 516];
  const int b = blockIdx.x;
  const int t = threadIdx.x;

  if (b < 1024) {  // ---- adj pack ----
    const int T = b * 256 + t;
    const int row = T >> 7, g = T & 127;
    const int* p = adj + (size_t)row * NN + g * 16;
    u32 m = 0;
#pragma unroll
    for (int q = 0; q < 4; ++q) {
      const int4 v = *(const int4*)&p[q * 4];
      m |= (v.x > 0 ? 1u : 0u) << (q * 4);
      m |= (v.y > 0 ? 2u : 0u) << (q * 4);
      m |= (v.z > 0 ? 4u : 0u) << (q * 4);
      m |= (v.w > 0 ? 8u : 0u) << (q * 4);
    }
    bits[T] = (unsigned short)m;
    return;
  }

  if (b < 1024 + 128) {  // ---- X -> Xf ----
    const int xb = b - 1024;
#pragma unroll
    for (int q = 0; q < 8; ++q) {
      const int flat = q * 256 + t;
      const int row = flat >> 7, c4 = flat & 127;
      const float4 v = *(const float4*)&X[(size_t)(xb * 16 + row) * KD + c4 * 4];
      *(float4*)&sbuf[row * 516 + c4 * 4] = v;
    }
    __syncthreads();
#pragma unroll
    for (int c = 0; c < 4; ++c) {
      const int s = c * 256 + t;
      const int l = s & 63;
      const int col = l & 15, kg = (l >> 4) & 3;
      const int k0 = (s >> 6) * 32 + kg * 8;
      bf16x8 o;
#pragma unroll
      for (int u = 0; u < 8; ++u) o[u] = tob(sbuf[col * 516 + k0 + u]);
      *(bf16x8*)&Xf[((size_t)xb * 1024 + s) * 8] = o;
    }
    return;
  }

  // ---- W -> Bf ----
  const int b2 = b - 1152;
  const int kb = b2 & 7, h = b2 >> 3;
  const int k0 = kb * 64;
#pragma unroll
  for (int q = 0; q < 4; ++q) {
    const int flat = q * 256 + t;
    const int kk = flat >> 4, o4 = (flat & 15) * 4;
    const float4 v = *(const float4*)&W[(size_t)(k0 + kk) * ODIM + h * 64 + o4];
    *(float4*)&sbuf[kk * 68 + o4] = v;
  }
  __syncthreads();
#pragma unroll
  for (int c = 0; c < 2; ++c) {
    const int s = c * 256 + t;
    const int ksl = s >> 8, nt = (s >> 6) & 3, l = s & 63;
    const int col = l & 15, kg = (l >> 4) & 3;
    const int kloc = ksl * 32 + kg * 8;
    const int od = nt * 16 + col;
    bf16x8 o;
#pragma unroll
    for (int u = 0; u < 8; ++u) o[u] = tob(sbuf[(kloc + u) * 68 + od]);
    const size_t off = (((size_t)(h * 4 + nt) * 16 + kb * 2 + ksl) * 64 + l) * 8;
    *(bf16x8*)&Bf[off] = o;
  }
}

// ---------------------------------------------------------------------------
// gemm_fused: grid (64, 8), 256 thr = 4 waves; block = 32 m-rows x head h.
// ---------------------------------------------------------------------------
__global__ __launch_bounds__(256) void gemm_fused(
    const short* __restrict__ Xf, const short* __restrict__ Bf,
    const float* __restrict__ a, short* __restrict__ WhF,
    float2* __restrict__ esrcp, u32* __restrict__ edstp) {
  __shared__ float pbuf[4 * 4 * 64 * 4];  // 16 KB
  const int t = threadIdx.x;
  const int lane = t & 63, w = t >> 6;
  const int col = lane & 15, kgrp = lane >> 4;
  const int bx = blockIdx.x;
  const int h = blockIdx.y;
  const int i0 = bx * 32;

  {
    const int mtg = bx * 2 + (w & 1);  // global 16-row m-tile
    const int kh = w >> 1;             // k-half
    const short* ax = Xf + (size_t)mtg * 8192;
    const short* bxp = Bf + (size_t)h * 32768;

    f32x4 acc1[4] = {};
#pragma unroll
    for (int k2 = 0; k2 < 8; ++k2) {
      const int ks = kh * 8 + k2;
      const bf16x8 af = *(const bf16x8*)&ax[(ks * 64 + lane) * 8];
#pragma unroll
      for (int nt = 0; nt < 4; ++nt) {
        const bf16x8 bf = *(const bf16x8*)&bxp[((nt * 16 + ks) * 64 + lane) * 8];
        acc1[nt] = __builtin_amdgcn_mfma_f32_16x16x32_bf16(af, bf, acc1[nt], 0, 0, 0);
      }
    }
#pragma unroll
    for (int nt = 0; nt < 4; ++nt)
      *(f32x4*)&pbuf[((w * 4 + nt) * 64 + lane) * 4] = acc1[nt];
  }
  __syncthreads();

  if (w < 2) {
    f32x4 acc[4];
#pragma unroll
    for (int nt = 0; nt < 4; ++nt) {
      const f32x4 p0 = *(const f32x4*)&pbuf[((w * 4 + nt) * 64 + lane) * 4];
      const f32x4 p1 = *(const f32x4*)&pbuf[(((w + 2) * 4 + nt) * 64 + lane) * 4];
      acc[nt] = p0 + p1;
    }
    float asv[4], adv[4];
#pragma unroll
    for (int nt = 0; nt < 4; ++nt) {
      asv[nt] = a[nt * 16 + col];
      adv[nt] = a[64 + nt * 16 + col];
    }
    float ps[4], pd[4];
#pragma unroll
    for (int r = 0; r < 4; ++r) {
      float s1 = 0.f, s2 = 0.f;
#pragma unroll
      for (int nt = 0; nt < 4; ++nt) {
        s1 += acc[nt][r] * asv[nt];
        s2 += acc[nt][r] * adv[nt];
      }
      ps[r] = s1;
      pd[r] = s2;
    }
#pragma unroll
    for (int off = 1; off <= 8; off <<= 1) {
#pragma unroll
      for (int r = 0; r < 4; ++r) {
        ps[r] += __shfl_xor(ps[r], off);
        pd[r] += __shfl_xor(pd[r], off);
      }
    }
    {
      const size_t tbase = ((size_t)h * 32 + (bx >> 1)) * 4096;
      const int lp = (w * 2 + (kgrp >> 1)) * 16 + col;
      const int u0 = (kgrp & 1) * 4;
      const int slot_ks = bx & 1;
#pragma unroll
      for (int nt = 0; nt < 4; ++nt) {
        bf16x4 o;
#pragma unroll
        for (int r = 0; r < 4; ++r) o[r] = tob(acc[nt][r]);
        *(bf16x4*)&WhF[tbase + (size_t)(nt * 2 + slot_ks) * 512 + lp * 8 + u0] = o;
      }
    }
    if (col == 0) {
      const int mbase = i0 + w * 16 + kgrp * 4;
#pragma unroll
      for (int r = 0; r < 4; ++r) {
        const int n = mbase + r;
        esrcp[h * NN + n] = make_float2(__expf(ps[r]), __expf(NEG * ps[r]));
        const u32 lo = (u32)(unsigned short)tob(__expf(pd[r]));
        const u32 hi = (u32)(unsigned short)tob(__expf(NEG * pd[r]));
        edstp[h * NN + n] = (hi << 16) | lo;
      }
    }
  }
}

// ---------------------------------------------------------------------------
// attn_mfma: R13 structure with WITHIN-TILE overlap (no extra state):
// eq reads issued FIRST, then b reads; lgkmcnt(8) (DS in-order: eq done,
// b in flight) -> p-gen overlaps b-read latency -> lgkmcnt(0) -> MFMA.
// p-gen uses v_cvt_pk_bf16_f32 (1 op per 2 elems convert+pack).
// ---------------------------------------------------------------------------
__global__ __launch_bounds__(512, 4) void attn_mfma(
    const short* __restrict__ WhF, const unsigned char* __restrict__ adjbits,
    const float2* __restrict__ esrcp, const u32* __restrict__ edstp,
    float* __restrict__ out) {
  extern __shared__ __align__(16) char smem[];  // 4 jq x 18432 B = 73728 B
  const int t = threadIdx.x;
  const int lane = t & 63;
  const int wid = t >> 6;
  const int jq = wid & 3;
  const int mh = wid >> 2;
  const int col = lane & 15, kgrp = lane >> 4;
  const int h = blockIdx.y;
  const int i0 = blockIdx.x * 32;
  const int irow = i0 + mh * 16;

  char* qbase = smem + jq * 18432;
  char* dbuf = qbase;          // [2][8192] B-fragments (shared by the pair)
  char* elds = qbase + 16384;  // 2048 B edstp

  const short* tb = WhF + ((size_t)h * 32 + jq * 8) * 4096;
  const int jb = jq * 512;

  const float2 e0 = esrcp[h * NN + irow + col];
  const float A0 = e0.x, C0 = e0.y;

  u64 aw[8];
  {
    const unsigned char* rb = adjbits + (size_t)(irow + col) * (NN / 8) + jq * 64;
#pragma unroll
    for (int q = 0; q < 4; ++q) {
      const uint4 v = *(const uint4*)(rb + q * 16);
      aw[q * 2] = (u64)v.x | ((u64)v.y << 32);
      aw[q * 2 + 1] = (u64)v.z | ((u64)v.w << 32);
    }
  }

  bf16x8 ones;
#pragma unroll
  for (int u = 0; u < 8; ++u) ones[u] = (short)0x3F80;

  f32x4 acc[4] = {};
  f32x4 accd = {};

  const u32 lread = to_lds(dbuf) + (u32)lane * 16u;
  const u32 eread = to_lds(elds) + (u32)kgrp * 32u;

  // ---- prologue: this wave stages its half of edstp + tile-0 slots ----
  {
    gl_lds16(edstp + h * NN + jb + mh * 256 + lane * 4, elds + mh * 1024);
#pragma unroll
    for (int s = 0; s < 4; ++s) {
      const int slot = mh * 4 + s;
      gl_lds16(tb + slot * 512 + lane * 8, dbuf + slot * 1024);
    }
  }

#pragma unroll
  for (int tt = 0; tt < 8; ++tt) {
    const int cur = tt & 1, nxt = cur ^ 1;

    // ---- issue this wave's 4 slots of tile tt+1, wait own tile-tt loads ----
    if (tt < 7) {
      const short* g = tb + (size_t)(tt + 1) * 4096;
      char* sb = dbuf + nxt * 8192;
#pragma unroll
      for (int s = 0; s < 4; ++s) {
        const int slot = mh * 4 + s;
        gl_lds16(g + slot * 512 + lane * 8, sb + slot * 1024);
      }
      asm volatile("s_waitcnt vmcnt(4)" ::: "memory");
    } else {
      asm volatile("s_waitcnt vmcnt(0)" ::: "memory");
    }
    __builtin_amdgcn_sched_barrier(0);
    __builtin_amdgcn_s_barrier();  // pair-join: partner's slots also landed

    // ---- eq reads FIRST, then b reads (DS completes in order) ----
    u32x4 eq[4];
    EQREAD(eq, tt);
    const u32 abuf = lread + (u32)(cur * 8192);
    bf16x8 b0, b1, b2, b3, b4, b5, b6, b7;
    DSR(b0, abuf, "0");
    DSR(b1, abuf, "1024");
    DSR(b2, abuf, "2048");
    DSR(b3, abuf, "3072");
    DSR(b4, abuf, "4096");
    DSR(b5, abuf, "5120");
    DSR(b6, abuf, "6144");
    DSR(b7, abuf, "7168");

    // ---- eq done (first 4 of 12); p-gen overlaps b-read latency ----
    asm volatile("s_waitcnt lgkmcnt(8)" ::: "memory");
    __builtin_amdgcn_sched_barrier(0);
    bf16x8 af[2];
    PGEN_PK(af, eq, aw[tt]);

    // ---- b done; MFMAs ----
    asm volatile("s_waitcnt lgkmcnt(0)" ::: "memory");
    __builtin_amdgcn_sched_barrier(0);

    __builtin_amdgcn_s_setprio(1);
    accd = __builtin_amdgcn_mfma_f32_16x16x32_bf16(af[0], ones, accd, 0, 0, 0);
    accd = __builtin_amdgcn_mfma_f32_16x16x32_bf16(af[1], ones, accd, 0, 0, 0);
    acc[0] = __builtin_amdgcn_mfma_f32_16x16x32_bf16(af[0], b0, acc[0], 0, 0, 0);
    acc[0] = __builtin_amdgcn_mfma_f32_16x16x32_bf16(af[1], b1, acc[0], 0, 0, 0);
    acc[1] = __builtin_amdgcn_mfma_f32_16x16x32_bf16(af[0], b2, acc[1], 0, 0, 0);
    acc[1] = __builtin_amdgcn_mfma_f32_16x16x32_bf16(af[1], b3, acc[1], 0, 0, 0);
    acc[2] = __builtin_amdgcn_mfma_f32_16x16x32_bf16(af[0], b4, acc[2], 0, 0, 0);
    acc[2] = __builtin_amdgcn_mfma_f32_16x16x32_bf16(af[1], b5, acc[2], 0, 0, 0);
    acc[3] = __builtin_amdgcn_mfma_f32_16x16x32_bf16(af[0], b6, acc[3], 0, 0, 0);
    acc[3] = __builtin_amdgcn_mfma_f32_16x16x32_bf16(af[1], b7, acc[3], 0, 0, 0);
    __builtin_amdgcn_s_setprio(0);

    __builtin_amdgcn_s_barrier();  // pair done reading cur -> safe to refill
  }

  // ---- cross-jq reduce (aliases dead staging LDS) ----
  __syncthreads();
  float* red = (float*)smem;  // [2 mh][4 jq][16 row][66]; den at col 64
  float* rw = red + (size_t)((mh * 4 + jq) * 16) * 66;
#pragma unroll
  for (int nt = 0; nt < 4; ++nt)
#pragma unroll
    for (int r = 0; r < 4; ++r)
      rw[(kgrp * 4 + r) * 66 + nt * 16 + col] = acc[nt][r];
  if (col == 0) {
#pragma unroll
    for (int r = 0; r < 4; ++r) rw[(kgrp * 4 + r) * 66 + 64] = accd[r];
  }
  __syncthreads();

  const int d = t & 63, idx = t >> 6;
#pragma unroll
  for (int rr = 0; rr < 4; ++rr) {
    const int row = rr * 8 + idx;
    const int mh2 = row >> 4, r16 = row & 15;
    float v = 0.f, dd = 0.f;
#pragma unroll
    for (int q = 0; q < 4; ++q) {
      const float* rb = red + (size_t)((mh2 * 4 + q) * 16 + r16) * 66;
      v += rb[d];
      dd += rb[64];
    }
    out[(size_t)(i0 + row) * ODIM + h * HD + d] = v / dd;
  }
}

// ---------------------------------------------------------------------------
extern "C" void kernel_launch(void* const* d_in, const int* in_sizes, int n_in,
                              void* d_out, int out_size, void* d_ws,
                              size_t ws_size, hipStream_t stream) {
  const float* x = (const float*)d_in[0];
  const int* adj = (const int*)d_in[1];
  const float* W = (const float*)d_in[2];
  const float* a = (const float*)d_in[3];
  float* out = (float*)d_out;

  char* ws = (char*)d_ws;
  short* WhF = (short*)ws;                                    // 2 MB
  short* Xf = (short*)(ws + (2 << 20));                       // 2 MB
  short* Bf = (short*)(ws + (4 << 20));                       // 512 KB
  unsigned short* bits =
      (unsigned short*)(ws + (4 << 20) + (512 << 10));        // 512 KB
  float2* esrcp = (float2*)(ws + (5 << 20));                  // 128 KB
  u32* edstp = (u32*)(ws + (5 << 20) + (128 << 10));          // 64 KB

  prep<<<1216, 256, 0, stream>>>(x, W, adj, Xf, Bf, bits);
  gemm_fused<<<dim3(64, 8), 256, 0, stream>>>(Xf, Bf, a, WhF, esrcp, edstp);
  attn_mfma<<<dim3(64, 8), 512, 73728, stream>>>(
      WhF, (const unsigned char*)bits, esrcp, edstp, out);
}

// Round 20
// 33.728 us; speedup vs baseline: 2.4740x; 1.0065x over previous
//
#include <hip/hip_runtime.h>
#include <hip/hip_bf16.h>

#define NN 2048
#define KD 512
#define ODIM 512
#define NHEAD 8
#define HD 64
#define NEG 0.2f

typedef float f32x4 __attribute__((ext_vector_type(4)));
typedef short bf16x8 __attribute__((ext_vector_type(8)));
typedef short bf16x4 __attribute__((ext_vector_type(4)));
typedef unsigned int u32x4 __attribute__((ext_vector_type(4)));
typedef unsigned long long u64;
typedef unsigned int u32;

typedef union {
  u32x4 w;
  bf16x8 h;
} pk8;

__device__ __forceinline__ short tob(float f) {
  __hip_bfloat16 h = __float2bfloat16(f);
  return *reinterpret_cast<short*>(&h);
}

// async global -> LDS; LDS dest = uniform base + lane*16; global src must
// already include the per-lane offset.
__device__ __forceinline__ void gl_lds16(const void* g, void* l) {
  __builtin_amdgcn_global_load_lds(
      (const __attribute__((address_space(1))) u32*)g,
      (__attribute__((address_space(3))) u32*)l, 16, 0, 0);
}

__device__ __forceinline__ u32 to_lds(const void* p) {
  return (u32)(size_t)(const __attribute__((address_space(3))) char*)p;
}

// inline-asm ds_read_b128: opaque to the waitcnt legalizer (no auto drains)
#define DSR(dst, addr, OFFLIT)                      \
  asm volatile("ds_read_b128 %0, %1 offset:" OFFLIT \
               : "=v"(dst)                          \
               : "v"(addr))

// per-jq LDS: dbuf [0,16384) | eB f32 [16384,18432) | eD bf16 [18432,19456)
#define QSTRIDE 19456

// ---------------------------------------------------------------------------
// prep: blocks 0..127  Xf: X (f32) -> bf16 in MFMA-A-fragment order
//       blocks 128..191 Bf: W (f32) -> bf16 in MFMA-B-fragment order
// ---------------------------------------------------------------------------
__global__ __launch_bounds__(256) void prep(const float* __restrict__ X,
                                            const float* __restrict__ W,
                                            short* __restrict__ Xf,
                                            short* __restrict__ Bf) {
  __shared__ float sbuf[16 * 516];
  const int b = blockIdx.x;
  const int t = threadIdx.x;

  if (b < 128) {  // ---- X -> Xf ----
    const int xb = b;
#pragma unroll
    for (int q = 0; q < 8; ++q) {
      const int flat = q * 256 + t;
      const int row = flat >> 7, c4 = flat & 127;
      const float4 v = *(const float4*)&X[(size_t)(xb * 16 + row) * KD + c4 * 4];
      *(float4*)&sbuf[row * 516 + c4 * 4] = v;
    }
    __syncthreads();
#pragma unroll
    for (int c = 0; c < 4; ++c) {
      const int s = c * 256 + t;
      const int l = s & 63;
      const int col = l & 15, kg = (l >> 4) & 3;
      const int k0 = (s >> 6) * 32 + kg * 8;
      bf16x8 o;
#pragma unroll
      for (int u = 0; u < 8; ++u) o[u] = tob(sbuf[col * 516 + k0 + u]);
      *(bf16x8*)&Xf[((size_t)xb * 1024 + s) * 8] = o;
    }
    return;
  }

  // ---- W -> Bf ----
  const int b2 = b - 128;
  const int kb = b2 & 7, h = b2 >> 3;
  const int k0 = kb * 64;
#pragma unroll
  for (int q = 0; q < 4; ++q) {
    const int flat = q * 256 + t;
    const int kk = flat >> 4, o4 = (flat & 15) * 4;
    const float4 v = *(const float4*)&W[(size_t)(k0 + kk) * ODIM + h * 64 + o4];
    *(float4*)&sbuf[kk * 68 + o4] = v;
  }
  __syncthreads();
#pragma unroll
  for (int c = 0; c < 2; ++c) {
    const int s = c * 256 + t;
    const int ksl = s >> 8, nt = (s >> 6) & 3, l = s & 63;
    const int col = l & 15, kg = (l >> 4) & 3;
    const int kloc = ksl * 32 + kg * 8;
    const int od = nt * 16 + col;
    bf16x8 o;
#pragma unroll
    for (int u = 0; u < 8; ++u) o[u] = tob(sbuf[(kloc + u) * 68 + od]);
    const size_t off = (((size_t)(h * 4 + nt) * 16 + kb * 2 + ksl) * 64 + l) * 8;
    *(bf16x8*)&Bf[off] = o;
  }
}

// ---------------------------------------------------------------------------
// gemm_adj: heterogeneous launch, 1536 blocks.
//   blocks 0..511: gemm (bx = b&63, h = b>>6) — Wh + exp tables (eB f32,
//                  eD bf16) + fragment-ordered WhF.
//   blocks 512..1535: adj int32 -> bitmask pack (memory-bound; overlaps the
//                  compute-bound gemm blocks on the CUs).
// ---------------------------------------------------------------------------
__global__ __launch_bounds__(256) void gemm_adj(
    const short* __restrict__ Xf, const short* __restrict__ Bf,
    const float* __restrict__ a, const int* __restrict__ adj,
    short* __restrict__ WhF, float2* __restrict__ esrcp,
    float* __restrict__ eB, unsigned short* __restrict__ eD,
    unsigned short* __restrict__ bits) {
  __shared__ float pbuf[4 * 4 * 64 * 4];  // 16 KB (gemm path only)
  const int b = blockIdx.x;
  const int t = threadIdx.x;

  if (b >= 512) {  // ---- adj pack ----
    const int T = (b - 512) * 256 + t;
    const int row = T >> 7, g = T & 127;
    const int* p = adj + (size_t)row * NN + g * 16;
    u32 m = 0;
#pragma unroll
    for (int q = 0; q < 4; ++q) {
      const int4 v = *(const int4*)&p[q * 4];
      m |= (v.x > 0 ? 1u : 0u) << (q * 4);
      m |= (v.y > 0 ? 2u : 0u) << (q * 4);
      m |= (v.z > 0 ? 4u : 0u) << (q * 4);
      m |= (v.w > 0 ? 8u : 0u) << (q * 4);
    }
    bits[T] = (unsigned short)m;
    return;
  }

  const int lane = t & 63, w = t >> 6;
  const int col = lane & 15, kgrp = lane >> 4;
  const int bx = b & 63;
  const int h = b >> 6;
  const int i0 = bx * 32;

  {
    const int mtg = bx * 2 + (w & 1);  // global 16-row m-tile
    const int kh = w >> 1;             // k-half
    const short* ax = Xf + (size_t)mtg * 8192;
    const short* bxp = Bf + (size_t)h * 32768;

    f32x4 acc1[4] = {};
#pragma unroll
    for (int k2 = 0; k2 < 8; ++k2) {
      const int ks = kh * 8 + k2;
      const bf16x8 af = *(const bf16x8*)&ax[(ks * 64 + lane) * 8];
#pragma unroll
      for (int nt = 0; nt < 4; ++nt) {
        const bf16x8 bf = *(const bf16x8*)&bxp[((nt * 16 + ks) * 64 + lane) * 8];
        acc1[nt] = __builtin_amdgcn_mfma_f32_16x16x32_bf16(af, bf, acc1[nt], 0, 0, 0);
      }
    }
#pragma unroll
    for (int nt = 0; nt < 4; ++nt)
      *(f32x4*)&pbuf[((w * 4 + nt) * 64 + lane) * 4] = acc1[nt];
  }
  __syncthreads();

  if (w < 2) {
    f32x4 acc[4];
#pragma unroll
    for (int nt = 0; nt < 4; ++nt) {
      const f32x4 p0 = *(const f32x4*)&pbuf[((w * 4 + nt) * 64 + lane) * 4];
      const f32x4 p1 = *(const f32x4*)&pbuf[(((w + 2) * 4 + nt) * 64 + lane) * 4];
      acc[nt] = p0 + p1;
    }
    float asv[4], adv[4];
#pragma unroll
    for (int nt = 0; nt < 4; ++nt) {
      asv[nt] = a[nt * 16 + col];
      adv[nt] = a[64 + nt * 16 + col];
    }
    float ps[4], pd[4];
#pragma unroll
    for (int r = 0; r < 4; ++r) {
      float s1 = 0.f, s2 = 0.f;
#pragma unroll
      for (int nt = 0; nt < 4; ++nt) {
        s1 += acc[nt][r] * asv[nt];
        s2 += acc[nt][r] * adv[nt];
      }
      ps[r] = s1;
      pd[r] = s2;
    }
#pragma unroll
    for (int off = 1; off <= 8; off <<= 1) {
#pragma unroll
      for (int r = 0; r < 4; ++r) {
        ps[r] += __shfl_xor(ps[r], off);
        pd[r] += __shfl_xor(pd[r], off);
      }
    }
    // fragment-ordered WhF store: j-tile = bx>>1, within-tile half = bx&1
    {
      const size_t tbase = ((size_t)h * 32 + (bx >> 1)) * 4096;
      const int lp = (w * 2 + (kgrp >> 1)) * 16 + col;
      const int u0 = (kgrp & 1) * 4;
      const int slot_ks = bx & 1;
#pragma unroll
      for (int nt = 0; nt < 4; ++nt) {
        bf16x4 o;
#pragma unroll
        for (int r = 0; r < 4; ++r) o[r] = tob(acc[nt][r]);
        *(bf16x4*)&WhF[tbase + (size_t)(nt * 2 + slot_ks) * 512 + lp * 8 + u0] = o;
      }
    }
    if (col == 0) {
      const int mbase = i0 + w * 16 + kgrp * 4;
#pragma unroll
      for (int r = 0; r < 4; ++r) {
        const int n = mbase + r;
        esrcp[h * NN + n] = make_float2(__expf(ps[r]), __expf(NEG * ps[r]));
        eB[h * NN + n] = __expf(pd[r]);
        eD[h * NN + n] = (unsigned short)tob(__expf(NEG * pd[r]));
      }
    }
  }
}

// ---------------------------------------------------------------------------
// attn_mfma: R18 structure; exp tables split as eB (f32, zero unpack) + eD
// (bf16, 1-op unpack), staged once per jq (WITH per-lane source offsets).
// Per tile: 6 eq reads + 8 b reads, lgkmcnt(8) -> p-gen overlaps b-read
// latency -> lgkmcnt(0) -> MFMA.
// ---------------------------------------------------------------------------
__global__ __launch_bounds__(512, 4) void attn_mfma(
    const short* __restrict__ WhF, const unsigned char* __restrict__ adjbits,
    const float2* __restrict__ esrcp, const float* __restrict__ eB,
    const unsigned short* __restrict__ eD, float* __restrict__ out) {
  extern __shared__ __align__(16) char smem[];  // 4 jq x QSTRIDE = 77824 B
  const int t = threadIdx.x;
  const int lane = t & 63;
  const int wid = t >> 6;
  const int jq = wid & 3;
  const int mh = wid >> 2;
  const int col = lane & 15, kgrp = lane >> 4;
  const int h = blockIdx.y;
  const int i0 = blockIdx.x * 32;
  const int irow = i0 + mh * 16;

  char* qbase = smem + jq * QSTRIDE;
  char* dbuf = qbase;           // [2][8192] B-fragments (pair-shared)
  char* eBl = qbase + 16384;    // 2048 B: eB f32 [8 tiles][64 j]
  char* eDl = qbase + 18432;    // 1024 B: eD bf16 [8 tiles][64 j]

  const short* tb = WhF + ((size_t)h * 32 + jq * 8) * 4096;
  const int jb = jq * 512;

  const float2 e0 = esrcp[h * NN + irow + col];
  const float A0 = e0.x, C0 = e0.y;

  u64 aw[8];
  {
    const unsigned char* rb = adjbits + (size_t)(irow + col) * (NN / 8) + jq * 64;
#pragma unroll
    for (int q = 0; q < 4; ++q) {
      const uint4 v = *(const uint4*)(rb + q * 16);
      aw[q * 2] = (u64)v.x | ((u64)v.y << 32);
      aw[q * 2 + 1] = (u64)v.z | ((u64)v.w << 32);
    }
  }

  bf16x8 ones;
#pragma unroll
  for (int u = 0; u < 8; ++u) ones[u] = (short)0x3F80;

  f32x4 acc[4] = {};
  f32x4 accd = {};

  const u32 lread = to_lds(dbuf) + (u32)lane * 16u;
  const u32 ereadB = to_lds(eBl) + (u32)kgrp * 32u;
  const u32 ereadD = to_lds(eDl) + (u32)kgrp * 16u;

  // ---- prologue: stage eB half (1 KB/wave), eD (1 KB, mh0), tile-0 slots.
  //      Global sources carry the per-lane lane*16 byte offset. ----
  {
    gl_lds16((const char*)eB + ((size_t)h * NN + jb) * 4 + mh * 1024 +
                 lane * 16,
             eBl + mh * 1024);
    if (mh == 0)
      gl_lds16((const char*)eD + ((size_t)h * NN + jb) * 2 + lane * 16, eDl);
#pragma unroll
    for (int s = 0; s < 4; ++s) {
      const int slot = mh * 4 + s;
      gl_lds16(tb + slot * 512 + lane * 8, dbuf + slot * 1024);
    }
  }

#pragma unroll
  for (int tt = 0; tt < 8; ++tt) {
    const int cur = tt & 1, nxt = cur ^ 1;

    // ---- issue this wave's 4 slots of tile tt+1, wait own tile-tt loads ----
    if (tt < 7) {
      const short* g = tb + (size_t)(tt + 1) * 4096;
      char* sb = dbuf + nxt * 8192;
#pragma unroll
      for (int s = 0; s < 4; ++s) {
        const int slot = mh * 4 + s;
        gl_lds16(g + slot * 512 + lane * 8, sb + slot * 1024);
      }
      asm volatile("s_waitcnt vmcnt(4)" ::: "memory");
    } else {
      asm volatile("s_waitcnt vmcnt(0)" ::: "memory");
    }
    __builtin_amdgcn_sched_barrier(0);
    __builtin_amdgcn_s_barrier();  // pair-join: partner's slots also landed

    // ---- eq reads FIRST (6), then b reads (8); DS completes in order ----
    const u32 erB = ereadB + (u32)(tt * 256);
    const u32 erD = ereadD + (u32)(tt * 128);
    u32x4 qb0, qb1, qb2, qb3, qd0, qd1;
    DSR(qb0, erB, "0");
    DSR(qb1, erB, "16");
    DSR(qb2, erB, "128");
    DSR(qb3, erB, "144");
    DSR(qd0, erD, "0");
    DSR(qd1, erD, "64");
    const u32 abuf = lread + (u32)(cur * 8192);
    bf16x8 b0, b1, b2, b3, b4, b5, b6, b7;
    DSR(b0, abuf, "0");
    DSR(b1, abuf, "1024");
    DSR(b2, abuf, "2048");
    DSR(b3, abuf, "3072");
    DSR(b4, abuf, "4096");
    DSR(b5, abuf, "5120");
    DSR(b6, abuf, "6144");
    DSR(b7, abuf, "7168");

    // ---- eq done (6 of 14); p-gen overlaps b-read latency ----
    asm volatile("s_waitcnt lgkmcnt(8)" ::: "memory");
    __builtin_amdgcn_sched_barrier(0);
    bf16x8 af[2];
#pragma unroll
    for (int ks = 0; ks < 2; ++ks) {
      const u32 mb = (u32)(aw[tt] >> ((ks * 4 + kgrp) * 8)) & 0xffu;
      const u32x4 qlo = ks ? qb2 : qb0;
      const u32x4 qhi = ks ? qb3 : qb1;
      const u32x4 qd = ks ? qd1 : qd0;
      float pv[8];
#pragma unroll
      for (int u2 = 0; u2 < 8; ++u2) {
        const u32 bw = (u2 < 4) ? qlo[u2 & 3] : qhi[u2 & 3];
        const float fB = __uint_as_float(bw);
        const u32 dw = qd[u2 >> 1];
        const float fD =
            __uint_as_float((u2 & 1) ? (dw & 0xffff0000u) : (dw << 16));
        const float p = fmaxf(A0 * fB, C0 * fD);
        pv[u2] = ((mb >> u2) & 1u) ? p : 0.f;
      }
      pk8 r;
#pragma unroll
      for (int w2 = 0; w2 < 4; ++w2) {
        u32 rr;
        asm("v_cvt_pk_bf16_f32 %0, %1, %2"
            : "=v"(rr)
            : "v"(pv[w2 * 2]), "v"(pv[w2 * 2 + 1]));
        r.w[w2] = rr;
      }
      af[ks] = r.h;
    }

    // ---- b done; MFMAs ----
    asm volatile("s_waitcnt lgkmcnt(0)" ::: "memory");
    __builtin_amdgcn_sched_barrier(0);

    __builtin_amdgcn_s_setprio(1);
    accd = __builtin_amdgcn_mfma_f32_16x16x32_bf16(af[0], ones, accd, 0, 0, 0);
    accd = __builtin_amdgcn_mfma_f32_16x16x32_bf16(af[1], ones, accd, 0, 0, 0);
    acc[0] = __builtin_amdgcn_mfma_f32_16x16x32_bf16(af[0], b0, acc[0], 0, 0, 0);
    acc[0] = __builtin_amdgcn_mfma_f32_16x16x32_bf16(af[1], b1, acc[0], 0, 0, 0);
    acc[1] = __builtin_amdgcn_mfma_f32_16x16x32_bf16(af[0], b2, acc[1], 0, 0, 0);
    acc[1] = __builtin_amdgcn_mfma_f32_16x16x32_bf16(af[1], b3, acc[1], 0, 0, 0);
    acc[2] = __builtin_amdgcn_mfma_f32_16x16x32_bf16(af[0], b4, acc[2], 0, 0, 0);
    acc[2] = __builtin_amdgcn_mfma_f32_16x16x32_bf16(af[1], b5, acc[2], 0, 0, 0);
    acc[3] = __builtin_amdgcn_mfma_f32_16x16x32_bf16(af[0], b6, acc[3], 0, 0, 0);
    acc[3] = __builtin_amdgcn_mfma_f32_16x16x32_bf16(af[1], b7, acc[3], 0, 0, 0);
    __builtin_amdgcn_s_setprio(0);

    __builtin_amdgcn_s_barrier();  // pair done reading cur -> safe to refill
  }

  // ---- cross-jq reduce (aliases dead staging LDS) ----
  __syncthreads();
  float* red = (float*)smem;  // [2 mh][4 jq][16 row][66]; den at col 64
  float* rw = red + (size_t)((mh * 4 + jq) * 16) * 66;
#pragma unroll
  for (int nt = 0; nt < 4; ++nt)
#pragma unroll
    for (int r = 0; r < 4; ++r)
      rw[(kgrp * 4 + r) * 66 + nt * 16 + col] = acc[nt][r];
  if (col == 0) {
#pragma unroll
    for (int r = 0; r < 4; ++r) rw[(kgrp * 4 + r) * 66 + 64] = accd[r];
  }
  __syncthreads();

  const int d = t & 63, idx = t >> 6;
#pragma unroll
  for (int rr = 0; rr < 4; ++rr) {
    const int row = rr * 8 + idx;
    const int mh2 = row >> 4, r16 = row & 15;
    float v = 0.f, dd = 0.f;
#pragma unroll
    for (int q = 0; q < 4; ++q) {
      const float* rb = red + (size_t)((mh2 * 4 + q) * 16 + r16) * 66;
      v += rb[d];
      dd += rb[64];
    }
    out[(size_t)(i0 + row) * ODIM + h * HD + d] = v / dd;
  }
}

// ---------------------------------------------------------------------------
extern "C" void kernel_launch(void* const* d_in, const int* in_sizes, int n_in,
                              void* d_out, int out_size, void* d_ws,
                              size_t ws_size, hipStream_t stream) {
  const float* x = (const float*)d_in[0];
  const int* adj = (const int*)d_in[1];
  const float* W = (const float*)d_in[2];
  const float* a = (const float*)d_in[3];
  float* out = (float*)d_out;

  char* ws = (char*)d_ws;
  short* WhF = (short*)ws;                                      // 2 MB
  short* Xf = (short*)(ws + (2 << 20));                         // 2 MB
  short* Bf = (short*)(ws + (4 << 20));                         // 512 KB
  unsigned short* bits =
      (unsigned short*)(ws + (4 << 20) + (512 << 10));          // 512 KB
  float2* esrcp = (float2*)(ws + (5 << 20));                    // 128 KB
  float* eB = (float*)(ws + (5 << 20) + (128 << 10));           // 64 KB
  unsigned short* eD =
      (unsigned short*)(ws + (5 << 20) + (192 << 10));          // 32 KB

  prep<<<192, 256, 0, stream>>>(x, W, Xf, Bf);
  gemm_adj<<<1536, 256, 0, stream>>>(Xf, Bf, a, adj, WhF, esrcp, eB, eD, bits);
  attn_mfma<<<dim3(64, 8), 512, 4 * QSTRIDE, stream>>>(
      WhF, (const unsigned char*)bits, esrcp, eB, eD, out);
}

// Round 21
// 33.504 us; speedup vs baseline: 2.4905x; 1.0067x over previous
//
#include <hip/hip_runtime.h>
#include <hip/hip_bf16.h>

#define NN 2048
#define KD 512
#define ODIM 512
#define NHEAD 8
#define HD 64
#define NEG 0.2f

typedef float f32x4 __attribute__((ext_vector_type(4)));
typedef short bf16x8 __attribute__((ext_vector_type(8)));
typedef short bf16x4 __attribute__((ext_vector_type(4)));
typedef unsigned int u32x4 __attribute__((ext_vector_type(4)));
typedef unsigned long long u64;
typedef unsigned int u32;

typedef union {
  u32x4 w;
  bf16x8 h;
} pk8;

__device__ __forceinline__ short tob(float f) {
  __hip_bfloat16 h = __float2bfloat16(f);
  return *reinterpret_cast<short*>(&h);
}

// async global -> LDS; LDS dest = uniform base + lane*16; global src must
// already include the per-lane offset.
__device__ __forceinline__ void gl_lds16(const void* g, void* l) {
  __builtin_amdgcn_global_load_lds(
      (const __attribute__((address_space(1))) u32*)g,
      (__attribute__((address_space(3))) u32*)l, 16, 0, 0);
}

__device__ __forceinline__ u32 to_lds(const void* p) {
  return (u32)(size_t)(const __attribute__((address_space(3))) char*)p;
}

// inline-asm ds_read_b128: opaque to the waitcnt legalizer (no auto drains)
#define DSR(dst, addr, OFFLIT)                      \
  asm volatile("ds_read_b128 %0, %1 offset:" OFFLIT \
               : "=v"(dst)                          \
               : "v"(addr))

// per-jq LDS: dbuf [0,16384) | eB f32 [16384,18432) | eD bf16 [18432,19456)
#define QSTRIDE 19456

// ---------------------------------------------------------------------------
// prep: blocks 0..127  Xf: X (f32) -> bf16 in MFMA-A-fragment order
//       blocks 128..191 Bf: W (f32) -> bf16 in MFMA-B-fragment order
// ---------------------------------------------------------------------------
__global__ __launch_bounds__(256) void prep(const float* __restrict__ X,
                                            const float* __restrict__ W,
                                            short* __restrict__ Xf,
                                            short* __restrict__ Bf) {
  __shared__ float sbuf[16 * 516];
  const int b = blockIdx.x;
  const int t = threadIdx.x;

  if (b < 128) {  // ---- X -> Xf ----
    const int xb = b;
#pragma unroll
    for (int q = 0; q < 8; ++q) {
      const int flat = q * 256 + t;
      const int row = flat >> 7, c4 = flat & 127;
      const float4 v = *(const float4*)&X[(size_t)(xb * 16 + row) * KD + c4 * 4];
      *(float4*)&sbuf[row * 516 + c4 * 4] = v;
    }
    __syncthreads();
#pragma unroll
    for (int c = 0; c < 4; ++c) {
      const int s = c * 256 + t;
      const int l = s & 63;
      const int col = l & 15, kg = (l >> 4) & 3;
      const int k0 = (s >> 6) * 32 + kg * 8;
      bf16x8 o;
#pragma unroll
      for (int u = 0; u < 8; ++u) o[u] = tob(sbuf[col * 516 + k0 + u]);
      *(bf16x8*)&Xf[((size_t)xb * 1024 + s) * 8] = o;
    }
    return;
  }

  // ---- W -> Bf ----
  const int b2 = b - 128;
  const int kb = b2 & 7, h = b2 >> 3;
  const int k0 = kb * 64;
#pragma unroll
  for (int q = 0; q < 4; ++q) {
    const int flat = q * 256 + t;
    const int kk = flat >> 4, o4 = (flat & 15) * 4;
    const float4 v = *(const float4*)&W[(size_t)(k0 + kk) * ODIM + h * 64 + o4];
    *(float4*)&sbuf[kk * 68 + o4] = v;
  }
  __syncthreads();
#pragma unroll
  for (int c = 0; c < 2; ++c) {
    const int s = c * 256 + t;
    const int ksl = s >> 8, nt = (s >> 6) & 3, l = s & 63;
    const int col = l & 15, kg = (l >> 4) & 3;
    const int kloc = ksl * 32 + kg * 8;
    const int od = nt * 16 + col;
    bf16x8 o;
#pragma unroll
    for (int u = 0; u < 8; ++u) o[u] = tob(sbuf[(kloc + u) * 68 + od]);
    const size_t off = (((size_t)(h * 4 + nt) * 16 + kb * 2 + ksl) * 64 + l) * 8;
    *(bf16x8*)&Bf[off] = o;
  }
}

// ---------------------------------------------------------------------------
// gemm_adj: heterogeneous launch, 1536 blocks.
//   blocks 0..511: gemm — Wh + exp tables (eB f32, eD bf16) + WhF.
//   blocks 512..1535: adj int32 -> bitmask pack (overlaps gemm on the CUs).
// ---------------------------------------------------------------------------
__global__ __launch_bounds__(256) void gemm_adj(
    const short* __restrict__ Xf, const short* __restrict__ Bf,
    const float* __restrict__ a, const int* __restrict__ adj,
    short* __restrict__ WhF, float2* __restrict__ esrcp,
    float* __restrict__ eB, unsigned short* __restrict__ eD,
    unsigned short* __restrict__ bits) {
  __shared__ float pbuf[4 * 4 * 64 * 4];  // 16 KB (gemm path only)
  const int b = blockIdx.x;
  const int t = threadIdx.x;

  if (b >= 512) {  // ---- adj pack ----
    const int T = (b - 512) * 256 + t;
    const int row = T >> 7, g = T & 127;
    const int* p = adj + (size_t)row * NN + g * 16;
    u32 m = 0;
#pragma unroll
    for (int q = 0; q < 4; ++q) {
      const int4 v = *(const int4*)&p[q * 4];
      m |= (v.x > 0 ? 1u : 0u) << (q * 4);
      m |= (v.y > 0 ? 2u : 0u) << (q * 4);
      m |= (v.z > 0 ? 4u : 0u) << (q * 4);
      m |= (v.w > 0 ? 8u : 0u) << (q * 4);
    }
    bits[T] = (unsigned short)m;
    return;
  }

  const int lane = t & 63, w = t >> 6;
  const int col = lane & 15, kgrp = lane >> 4;
  const int bx = b & 63;
  const int h = b >> 6;
  const int i0 = bx * 32;

  {
    const int mtg = bx * 2 + (w & 1);  // global 16-row m-tile
    const int kh = w >> 1;             // k-half
    const short* ax = Xf + (size_t)mtg * 8192;
    const short* bxp = Bf + (size_t)h * 32768;

    f32x4 acc1[4] = {};
#pragma unroll
    for (int k2 = 0; k2 < 8; ++k2) {
      const int ks = kh * 8 + k2;
      const bf16x8 af = *(const bf16x8*)&ax[(ks * 64 + lane) * 8];
#pragma unroll
      for (int nt = 0; nt < 4; ++nt) {
        const bf16x8 bf = *(const bf16x8*)&bxp[((nt * 16 + ks) * 64 + lane) * 8];
        acc1[nt] = __builtin_amdgcn_mfma_f32_16x16x32_bf16(af, bf, acc1[nt], 0, 0, 0);
      }
    }
#pragma unroll
    for (int nt = 0; nt < 4; ++nt)
      *(f32x4*)&pbuf[((w * 4 + nt) * 64 + lane) * 4] = acc1[nt];
  }
  __syncthreads();

  if (w < 2) {
    f32x4 acc[4];
#pragma unroll
    for (int nt = 0; nt < 4; ++nt) {
      const f32x4 p0 = *(const f32x4*)&pbuf[((w * 4 + nt) * 64 + lane) * 4];
      const f32x4 p1 = *(const f32x4*)&pbuf[(((w + 2) * 4 + nt) * 64 + lane) * 4];
      acc[nt] = p0 + p1;
    }
    float asv[4], adv[4];
#pragma unroll
    for (int nt = 0; nt < 4; ++nt) {
      asv[nt] = a[nt * 16 + col];
      adv[nt] = a[64 + nt * 16 + col];
    }
    float ps[4], pd[4];
#pragma unroll
    for (int r = 0; r < 4; ++r) {
      float s1 = 0.f, s2 = 0.f;
#pragma unroll
      for (int nt = 0; nt < 4; ++nt) {
        s1 += acc[nt][r] * asv[nt];
        s2 += acc[nt][r] * adv[nt];
      }
      ps[r] = s1;
      pd[r] = s2;
    }
#pragma unroll
    for (int off = 1; off <= 8; off <<= 1) {
#pragma unroll
      for (int r = 0; r < 4; ++r) {
        ps[r] += __shfl_xor(ps[r], off);
        pd[r] += __shfl_xor(pd[r], off);
      }
    }
    {
      const size_t tbase = ((size_t)h * 32 + (bx >> 1)) * 4096;
      const int lp = (w * 2 + (kgrp >> 1)) * 16 + col;
      const int u0 = (kgrp & 1) * 4;
      const int slot_ks = bx & 1;
#pragma unroll
      for (int nt = 0; nt < 4; ++nt) {
        bf16x4 o;
#pragma unroll
        for (int r = 0; r < 4; ++r) o[r] = tob(acc[nt][r]);
        *(bf16x4*)&WhF[tbase + (size_t)(nt * 2 + slot_ks) * 512 + lp * 8 + u0] = o;
      }
    }
    if (col == 0) {
      const int mbase = i0 + w * 16 + kgrp * 4;
#pragma unroll
      for (int r = 0; r < 4; ++r) {
        const int n = mbase + r;
        esrcp[h * NN + n] = make_float2(__expf(ps[r]), __expf(NEG * ps[r]));
        eB[h * NN + n] = __expf(pd[r]);
        eD[h * NN + n] = (unsigned short)tob(__expf(NEG * pd[r]));
      }
    }
  }
}

// ---------------------------------------------------------------------------
// attn_mfma: grid (32, 8) = 256 blocks = 1/CU, 1024 thr = 16 waves =
// 4 jq x 4 mh (64 i-rows/block). Each jq's double-buffer shared by 4 waves:
// each wave stages 2 of 8 slots per tile (vmcnt(2)); B-fragment L2 traffic
// and DMA count HALVED vs 32-row blocks. Same 16 waves/CU. Pipeline
// unchanged: eq reads first -> lgkmcnt(8) -> p-gen overlaps b reads ->
// lgkmcnt(0) -> MFMA; raw s_barrier (block-wide) pairs per tile.
// ---------------------------------------------------------------------------
__global__ __launch_bounds__(1024, 4) void attn_mfma(
    const short* __restrict__ WhF, const unsigned char* __restrict__ adjbits,
    const float2* __restrict__ esrcp, const float* __restrict__ eB,
    const unsigned short* __restrict__ eD, float* __restrict__ out) {
  extern __shared__ __align__(16) char smem[];  // 4 jq x QSTRIDE = 77824 B
  const int t = threadIdx.x;
  const int lane = t & 63;
  const int wid = t >> 6;   // 0..15
  const int jq = wid & 3;
  const int mh = wid >> 2;  // 0..3
  const int col = lane & 15, kgrp = lane >> 4;
  const int h = blockIdx.y;
  const int i0 = blockIdx.x * 64;
  const int irow = i0 + mh * 16;

  char* qbase = smem + jq * QSTRIDE;
  char* dbuf = qbase;           // [2][8192] B-fragments (shared by 4 waves)
  char* eBl = qbase + 16384;    // 2048 B: eB f32 [8 tiles][64 j]
  char* eDl = qbase + 18432;    // 1024 B: eD bf16 [8 tiles][64 j]

  const short* tb = WhF + ((size_t)h * 32 + jq * 8) * 4096;
  const int jb = jq * 512;

  const float2 e0 = esrcp[h * NN + irow + col];
  const float A0 = e0.x, C0 = e0.y;

  u64 aw[8];
  {
    const unsigned char* rb = adjbits + (size_t)(irow + col) * (NN / 8) + jq * 64;
#pragma unroll
    for (int q = 0; q < 4; ++q) {
      const uint4 v = *(const uint4*)(rb + q * 16);
      aw[q * 2] = (u64)v.x | ((u64)v.y << 32);
      aw[q * 2 + 1] = (u64)v.z | ((u64)v.w << 32);
    }
  }

  bf16x8 ones;
#pragma unroll
  for (int u = 0; u < 8; ++u) ones[u] = (short)0x3F80;

  f32x4 acc[4] = {};
  f32x4 accd = {};

  const u32 lread = to_lds(dbuf) + (u32)lane * 16u;
  const u32 ereadB = to_lds(eBl) + (u32)kgrp * 32u;
  const u32 ereadD = to_lds(eDl) + (u32)kgrp * 16u;

  // ---- prologue: scalars split across mh waves + tile-0 slots (2/wave) ----
  {
    if (mh == 0)
      gl_lds16((const char*)eB + ((size_t)h * NN + jb) * 4 + lane * 16, eBl);
    else if (mh == 1)
      gl_lds16((const char*)eB + ((size_t)h * NN + jb) * 4 + 1024 + lane * 16,
               eBl + 1024);
    else if (mh == 2)
      gl_lds16((const char*)eD + ((size_t)h * NN + jb) * 2 + lane * 16, eDl);
#pragma unroll
    for (int s = 0; s < 2; ++s) {
      const int slot = mh * 2 + s;
      gl_lds16(tb + slot * 512 + lane * 8, dbuf + slot * 1024);
    }
  }

#pragma unroll
  for (int tt = 0; tt < 8; ++tt) {
    const int cur = tt & 1, nxt = cur ^ 1;

    // ---- issue this wave's 2 slots of tile tt+1, wait own tile-tt loads ----
    if (tt < 7) {
      const short* g = tb + (size_t)(tt + 1) * 4096;
      char* sb = dbuf + nxt * 8192;
#pragma unroll
      for (int s = 0; s < 2; ++s) {
        const int slot = mh * 2 + s;
        gl_lds16(g + slot * 512 + lane * 8, sb + slot * 1024);
      }
      asm volatile("s_waitcnt vmcnt(2)" ::: "memory");
    } else {
      asm volatile("s_waitcnt vmcnt(0)" ::: "memory");
    }
    __builtin_amdgcn_sched_barrier(0);
    __builtin_amdgcn_s_barrier();  // block-wide join: all slots landed

    // ---- eq reads FIRST (6), then b reads (8); DS completes in order ----
    const u32 erB = ereadB + (u32)(tt * 256);
    const u32 erD = ereadD + (u32)(tt * 128);
    u32x4 qb0, qb1, qb2, qb3, qd0, qd1;
    DSR(qb0, erB, "0");
    DSR(qb1, erB, "16");
    DSR(qb2, erB, "128");
    DSR(qb3, erB, "144");
    DSR(qd0, erD, "0");
    DSR(qd1, erD, "64");
    const u32 abuf = lread + (u32)(cur * 8192);
    bf16x8 b0, b1, b2, b3, b4, b5, b6, b7;
    DSR(b0, abuf, "0");
    DSR(b1, abuf, "1024");
    DSR(b2, abuf, "2048");
    DSR(b3, abuf, "3072");
    DSR(b4, abuf, "4096");
    DSR(b5, abuf, "5120");
    DSR(b6, abuf, "6144");
    DSR(b7, abuf, "7168");

    // ---- eq done (6 of 14); p-gen overlaps b-read latency ----
    asm volatile("s_waitcnt lgkmcnt(8)" ::: "memory");
    __builtin_amdgcn_sched_barrier(0);
    bf16x8 af[2];
#pragma unroll
    for (int ks = 0; ks < 2; ++ks) {
      const u32 mb = (u32)(aw[tt] >> ((ks * 4 + kgrp) * 8)) & 0xffu;
      const u32x4 qlo = ks ? qb2 : qb0;
      const u32x4 qhi = ks ? qb3 : qb1;
      const u32x4 qd = ks ? qd1 : qd0;
      float pv[8];
#pragma unroll
      for (int u2 = 0; u2 < 8; ++u2) {
        const u32 bw = (u2 < 4) ? qlo[u2 & 3] : qhi[u2 & 3];
        const float fB = __uint_as_float(bw);
        const u32 dw = qd[u2 >> 1];
        const float fD =
            __uint_as_float((u2 & 1) ? (dw & 0xffff0000u) : (dw << 16));
        const float p = fmaxf(A0 * fB, C0 * fD);
        pv[u2] = ((mb >> u2) & 1u) ? p : 0.f;
      }
      pk8 r;
#pragma unroll
      for (int w2 = 0; w2 < 4; ++w2) {
        u32 rr;
        asm("v_cvt_pk_bf16_f32 %0, %1, %2"
            : "=v"(rr)
            : "v"(pv[w2 * 2]), "v"(pv[w2 * 2 + 1]));
        r.w[w2] = rr;
      }
      af[ks] = r.h;
    }

    // ---- b done; MFMAs ----
    asm volatile("s_waitcnt lgkmcnt(0)" ::: "memory");
    __builtin_amdgcn_sched_barrier(0);

    __builtin_amdgcn_s_setprio(1);
    accd = __builtin_amdgcn_mfma_f32_16x16x32_bf16(af[0], ones, accd, 0, 0, 0);
    accd = __builtin_amdgcn_mfma_f32_16x16x32_bf16(af[1], ones, accd, 0, 0, 0);
    acc[0] = __builtin_amdgcn_mfma_f32_16x16x32_bf16(af[0], b0, acc[0], 0, 0, 0);
    acc[0] = __builtin_amdgcn_mfma_f32_16x16x32_bf16(af[1], b1, acc[0], 0, 0, 0);
    acc[1] = __builtin_amdgcn_mfma_f32_16x16x32_bf16(af[0], b2, acc[1], 0, 0, 0);
    acc[1] = __builtin_amdgcn_mfma_f32_16x16x32_bf16(af[1], b3, acc[1], 0, 0, 0);
    acc[2] = __builtin_amdgcn_mfma_f32_16x16x32_bf16(af[0], b4, acc[2], 0, 0, 0);
    acc[2] = __builtin_amdgcn_mfma_f32_16x16x32_bf16(af[1], b5, acc[2], 0, 0, 0);
    acc[3] = __builtin_amdgcn_mfma_f32_16x16x32_bf16(af[0], b6, acc[3], 0, 0, 0);
    acc[3] = __builtin_amdgcn_mfma_f32_16x16x32_bf16(af[1], b7, acc[3], 0, 0, 0);
    __builtin_amdgcn_s_setprio(0);

    __builtin_amdgcn_s_barrier();  // all waves done reading cur -> refill ok
  }

  // ---- cross-jq reduce (aliases dead staging LDS) ----
  __syncthreads();
  float* red = (float*)smem;  // [4 mh][4 jq][16 row][66]; den at col 64
  float* rw = red + (size_t)((mh * 4 + jq) * 16) * 66;
#pragma unroll
  for (int nt = 0; nt < 4; ++nt)
#pragma unroll
    for (int r = 0; r < 4; ++r)
      rw[(kgrp * 4 + r) * 66 + nt * 16 + col] = acc[nt][r];
  if (col == 0) {
#pragma unroll
    for (int r = 0; r < 4; ++r) rw[(kgrp * 4 + r) * 66 + 64] = accd[r];
  }
  __syncthreads();

  const int d = t & 63, idx = t >> 6;  // idx 0..15
#pragma unroll
  for (int rr = 0; rr < 4; ++rr) {
    const int row = rr * 16 + idx;  // 0..63
    const int mh2 = row >> 4, r16 = row & 15;
    float v = 0.f, dd = 0.f;
#pragma unroll
    for (int q = 0; q < 4; ++q) {
      const float* rb = red + (size_t)((mh2 * 4 + q) * 16 + r16) * 66;
      v += rb[d];
      dd += rb[64];
    }
    out[(size_t)(i0 + row) * ODIM + h * HD + d] = v / dd;
  }
}

// ---------------------------------------------------------------------------
extern "C" void kernel_launch(void* const* d_in, const int* in_sizes, int n_in,
                              void* d_out, int out_size, void* d_ws,
                              size_t ws_size, hipStream_t stream) {
  const float* x = (const float*)d_in[0];
  const int* adj = (const int*)d_in[1];
  const float* W = (const float*)d_in[2];
  const float* a = (const float*)d_in[3];
  float* out = (float*)d_out;

  char* ws = (char*)d_ws;
  short* WhF = (short*)ws;                                      // 2 MB
  short* Xf = (short*)(ws + (2 << 20));                         // 2 MB
  short* Bf = (short*)(ws + (4 << 20));                         // 512 KB
  unsigned short* bits =
      (unsigned short*)(ws + (4 << 20) + (512 << 10));          // 512 KB
  float2* esrcp = (float2*)(ws + (5 << 20));                    // 128 KB
  float* eB = (float*)(ws + (5 << 20) + (128 << 10));           // 64 KB
  unsigned short* eD =
      (unsigned short*)(ws + (5 << 20) + (192 << 10));          // 32 KB

  prep<<<192, 256, 0, stream>>>(x, W, Xf, Bf);
  gemm_adj<<<1536, 256, 0, stream>>>(Xf, Bf, a, adj, WhF, esrcp, eB, eD, bits);
  attn_mfma<<<dim3(32, 8), 1024, 4 * QSTRIDE, stream>>>(
      WhF, (const unsigned char*)bits, esrcp, eB, eD, out);
}